// Round 7
// baseline (372.607 us; speedup 1.0000x reference)
//
#include <hip/hip_runtime.h>
#include <hip/hip_fp16.h>

typedef unsigned short u16;
typedef __attribute__((ext_vector_type(8))) short bf16x8;
typedef __attribute__((ext_vector_type(4))) float f32x4;

constexpr int B_ = 2, C_ = 128, H_ = 256, W_ = 256, P_ = H_ * W_;
constexpr int HP_ = 258, WP_ = 258;

union HU { __half2 h; unsigned int u; };

__device__ __forceinline__ float bf2f(u16 u) {
  union { unsigned int i; float f; } v; v.i = ((unsigned int)u) << 16; return v.f;
}
__device__ __forceinline__ u16 f2bf(float f) {
  union { float f; unsigned int i; } v; v.f = f;
  return (u16)((v.i + 0x7fffu + ((v.i >> 16) & 1u)) >> 16);  // RNE
}
// tanh-form GELU via sigmoid; |dev from erf-GELU| <= ~5e-4
__device__ __forceinline__ float gelu_f(float x) {
  float u = x * (1.5957691216057308f + 0.071354816272f * x * x);
  return x / (1.0f + __expf(-u));
}

// async global->LDS, 16B per lane. LDS dest must be wave-uniform base + lane*16.
__device__ __forceinline__ void async16(const u16* g, u16* l) {
  __builtin_amdgcn_global_load_lds(
      (const __attribute__((address_space(1))) unsigned int*)g,
      (__attribute__((address_space(3))) unsigned int*)l, 16, 0, 0);
}

// ---------------- prologue: to_nhwc(q), to_nhwc(key), border-zero x2, repack ----------
// grid: [0,8192) nhwc transposes; [8192,10256) border; [10256,11176) repack
__global__ __launch_bounds__(256) void prologue(
    const float* __restrict__ q, const float* __restrict__ key,
    const float* __restrict__ ow1, const float* __restrict__ ow2,
    const float* __restrict__ ww1, const float* __restrict__ fw1,
    const float* __restrict__ fw2,
    u16* __restrict__ qpad, u16* __restrict__ keyn, u16* __restrict__ t1pad,
    u16* __restrict__ wb) {
  __shared__ u16 l[64 * 66];
  const int id = blockIdx.x, tid = threadIdx.x;
  if (id < 8192) {
    int z = id >> 10, r = id & 1023;
    int bx = r & 3, by = r >> 2;
    const float* in; u16* out; int OW, opad;
    if (z < 4) { in = q; out = qpad; OW = WP_; opad = 1; }
    else { z -= 4; in = key; out = keyn; OW = W_; opad = 0; }
    int b = z >> 1, c0 = (z & 1) * 64;
    int h = by, w0 = bx * 64;
    for (int it = 0; it < 16; ++it) {
      int lin = it * 256 + tid;
      int c = lin >> 6, w = lin & 63;
      l[c * 66 + w] = f2bf(in[(((size_t)b * C_ + c0 + c) * H_ + h) * W_ + w0 + w]);
    }
    __syncthreads();
    int OH = (opad ? HP_ : H_);
    for (int it = 0; it < 16; ++it) {
      int lin = it * 256 + tid;
      int w = lin >> 6, c = lin & 63;
      out[(((size_t)b * OH + h + opad) * OW + (w0 + w + opad)) * C_ + c0 + c] = l[c * 66 + w];
    }
  } else if (id < 10256) {
    int j = id - 8192;
    u16* buf = (j < 1032) ? qpad : t1pad;
    int idx = ((j < 1032) ? j : j - 1032) * 256 + tid;
    int c = idx & 127;
    int t = idx >> 7;
    int pos = t % 258;
    int side = (t / 258) & 3;
    int b = t / (258 * 4);
    int h, w;
    if (side == 0) { h = 0; w = pos; }
    else if (side == 1) { h = 257; w = pos; }
    else if (side == 2) { h = pos; w = 0; }
    else { h = pos; w = 257; }
    buf[(((size_t)b * HP_ + h) * WP_ + w) * C_ + c] = 0;
  } else {
    // repack weights into wbuf (bf16):
    // W1c @0: ow1+ww1 fragment-packed [tap][cq][g 10][kb 4][lr 16][e 8] = 184320
    // W2 @184320: ow2 packed GT=1, co 8->16 zero-pad = 18432
    // fw1 @202752 row-major [co][ci] 16384 ; fw2 @219136 row-major 16384
    int idx = (id - 10256) * 256 + tid;
    float v;
    if (idx < 184320) {
      int e = idx & 7, lr = (idx >> 3) & 15, kb = (idx >> 7) & 3;
      int t = idx >> 9;
      int g = t % 10, u = t / 10;
      int cq = u & 3, tap = u >> 2;
      int ci = cq * 32 + kb * 8 + e, co = g * 16 + lr;
      v = (co < 128) ? ow1[(co * 128 + ci) * 9 + tap]
                     : ww1[((co - 128) * 128 + ci) * 9 + tap];
    } else if (idx < 202752) {
      int j = idx - 184320;
      int e = j & 7, lr = (j >> 3) & 15, kb = (j >> 7) & 3;
      int cq = (j >> 9) & 3, tap = j >> 11;
      int ci = cq * 32 + kb * 8 + e, co = lr;
      v = (co < 8) ? ow2[(co * 128 + ci) * 9 + tap] : 0.0f;
    } else if (idx < 219136) {
      v = fw1[idx - 202752];
    } else {
      v = fw2[idx - 219136];
    }
    wb[idx] = f2bf(v);
  }
}

// ---------------- combined 3x3 conv (ow1 128->128 + ww1 128->32), band-tiled ----------
// 512 threads = 8 waves; per-wave 2x5 acc tiles (40 AGPR).
// BM=128 as 4 rows x 32 px; BN=160 (GT=10); A staged per ci-quarter (double-buffered,
// prefetched before compute — R2-measured structure). NEW (register-only delta):
// weight fragments software-pipelined ONE TAP AHEAD in VGPRs (bcur/bnext[5]) so the
// ~200-300cy L2 latency of the 5 per-tap fragment loads hides under the 10 MFMAs of
// the previous tap. No new LDS, no new barriers.
__global__ __launch_bounds__(512, 4) void conv3_big(
    const u16* __restrict__ A, const u16* __restrict__ Wf,
    const float* __restrict__ bias1, const float* __restrict__ bias2,
    u16* __restrict__ outb, u16* __restrict__ outw) {
  constexpr int RPX = 36, ROWU = RPX * 32;          // u16 per row-plane = 1152
  __shared__ __align__(16) u16 As[2][6 * ROWU];     // 2 x 13,824 B double buffer
  const int tid = threadIdx.x, lane = tid & 63, wave = tid >> 6;  // 8 waves
  const int id = blockIdx.x;
  const int s = id >> 3;
  const int h0 = (((id & 7) << 3) | (s & 7)) << 2;  // 4-row band
  const int w0 = ((s >> 3) & 7) << 5;
  const int b = s >> 6;
  const int wr = wave >> 1, wc = wave & 1;          // wr: row 0..3, wc: co half
  const int wn = wc * 80;
  const int lr = lane & 15, kq = lane >> 4;
  const int gbase = wn >> 4;                        // 0 or 5

  int preA[2][3];
#pragma unroll
  for (int i = 0; i < 2; i++)
#pragma unroll
    for (int kx = 0; kx < 3; kx++) {
      int pxv = i * 16 + lr + kx;
      preA[i][kx] = (pxv * 4 + (kq ^ ((pxv >> 1) & 3))) * 8;  // u16 units
    }

  // A staging slots (i = tid, tid+512), hoisted out of the loop.
  size_t soff0, soff1;
  int doff0, doff1;
  const bool has2 = (tid + 512 < 864);
  {
    int i = tid;
    int ry = i / 144;
    int rem = i - ry * 144;
    int px = rem >> 2, c8 = rem & 3;
    int g = c8 ^ ((px >> 1) & 3);
    soff0 = ((size_t)(b * HP_ + h0 + ry) * WP_ + (w0 + px)) * 128 + g * 8;
    doff0 = i * 8;
  }
  {
    int i = (tid + 512 < 864) ? tid + 512 : tid;  // clamp: unused when !has2
    int ry = i / 144;
    int rem = i - ry * 144;
    int px = rem >> 2, c8 = rem & 3;
    int g = c8 ^ ((px >> 1) & 3);
    soff1 = ((size_t)(b * HP_ + h0 + ry) * WP_ + (w0 + px)) * 128 + g * 8;
    doff1 = i * 8;
  }

  // per-thread weight base: W(tap,cq,j) = Wt + (tap*4+cq)*5120 + j*512
  const u16* Wt = Wf + gbase * 512 + kq * 128 + lr * 8;

  f32x4 acc[2][5];
#pragma unroll
  for (int i = 0; i < 2; i++)
#pragma unroll
    for (int j = 0; j < 5; j++) { f32x4 z = {0.f, 0.f, 0.f, 0.f}; acc[i][j] = z; }

  // prologue stage: ci-quarter 0 into buffer 0
  async16(A + soff0, As[0] + doff0);
  if (has2) async16(A + soff1, As[0] + doff1);
  __syncthreads();

  // preload weights for (tap0, cq0)
  bf16x8 bcur[5];
#pragma unroll
  for (int j = 0; j < 5; ++j) bcur[j] = *(const bf16x8*)&Wt[j * 512];

  for (int cq = 0; cq < 4; ++cq) {
    // issue next-quarter A stage into the other buffer BEFORE compute
    if (cq < 3) {
      const int ci0 = (cq + 1) * 32;
      u16* dst = As[(cq + 1) & 1];
      async16(A + soff0 + ci0, dst + doff0);
      if (has2) async16(A + soff1 + ci0, dst + doff1);
    }
    const u16* Ac = As[cq & 1];
#pragma unroll
    for (int tap = 0; tap < 9; ++tap) {
      const int ky = tap / 3, kx = tap % 3;
      // prefetch next tap's weights (crossing the cq boundary at tap 8)
      const int ntc = (tap < 8) ? ((tap + 1) * 4 + cq) : ((cq < 3) ? (cq + 1) : -1);
      bf16x8 bnext[5];
      if (ntc >= 0) {
        const u16* p = Wt + (size_t)ntc * 5120;
#pragma unroll
        for (int j = 0; j < 5; ++j) bnext[j] = *(const bf16x8*)&p[j * 512];
      }
      bf16x8 af[2];
#pragma unroll
      for (int i = 0; i < 2; ++i)
        af[i] = *(const bf16x8*)&Ac[(wr + ky) * ROWU + preA[i][kx]];
#pragma unroll
      for (int i = 0; i < 2; i++)
#pragma unroll
        for (int j = 0; j < 5; j++)
          acc[i][j] = __builtin_amdgcn_mfma_f32_16x16x32_bf16(af[i], bcur[j], acc[i][j], 0, 0, 0);
      if (ntc >= 0) {
#pragma unroll
        for (int j = 0; j < 5; ++j) bcur[j] = bnext[j];
      }
    }
    // single barrier per cq: drains the A prefetch (covered by 90 MFMAs)
    // and protects the As buffer we overwrite next iter.
    if (cq < 3) __syncthreads();
  }

  const int h = h0 + wr;
#pragma unroll
  for (int i = 0; i < 2; i++) {
#pragma unroll
    for (int j = 0; j < 5; j++) {
      const int co = wn + j * 16 + lr;
#pragma unroll
      for (int r = 0; r < 4; r++) {
        const int w = w0 + i * 16 + kq * 4 + r;
        float v = acc[i][j][r];
        if (co < 128) {
          v = gelu_f(v + bias1[co]);
          outb[(((size_t)b * HP_ + h + 1) * WP_ + (w + 1)) * 128 + co] = f2bf(v);
        } else {
          v = gelu_f(v + bias2[co - 128]);
          outw[((size_t)b * P_ + (size_t)h * W_ + w) * 32 + (co - 128)] = f2bf(v);
        }
      }
    }
  }
}

// ---------------- offsets conv (3x3 128->8) + fused prep epilogue ---------------------
// BM=256 as 4 rows x 64 px; BN=16; wave = one row. Epilogue: offs->LDS regroup,
// then per-thread pixel: logits(32->4), softmax, grid math -> desc.
__global__ __launch_bounds__(256) void conv_off(
    const u16* __restrict__ A, const u16* __restrict__ Wf,
    const float* __restrict__ bias,
    const u16* __restrict__ w1b, const float* __restrict__ ww2,
    const float* __restrict__ wb2, uint4* __restrict__ desc) {
  constexpr int RPX = 66, ROWU = RPX * 32;          // 2112 u16 per row-plane
  __shared__ __align__(16) u16 As[6 * ROWU];        // 25,344 B
  float* off_lds = (float*)As;                      // reused after K-loop (256*9*4 B)
  const int tid = threadIdx.x, lane = tid & 63, wave = tid >> 6;
  const int id = blockIdx.x;
  const int s = id >> 3;
  const int h0 = (((id & 7) << 3) | (s & 7)) << 2;
  const int w0 = ((s >> 3) & 3) << 6;
  const int b = s >> 5;
  const int lr = lane & 15, kq = lane >> 4;

  int preA[4][3];
#pragma unroll
  for (int i = 0; i < 4; i++)
#pragma unroll
    for (int kx = 0; kx < 3; kx++) {
      int pxv = i * 16 + lr + kx;
      preA[i][kx] = (pxv * 4 + (kq ^ ((pxv >> 1) & 3))) * 8;
    }

  f32x4 acc[4];
#pragma unroll
  for (int i = 0; i < 4; i++) { f32x4 z = {0.f, 0.f, 0.f, 0.f}; acc[i] = z; }

  for (int cq = 0; cq < 4; ++cq) {
    const int ci0 = cq * 32;
    __syncthreads();
    for (int i = tid; i < 1584; i += 256) {
      int ry = i / 264;
      int rem = i - ry * 264;
      int px = rem >> 2, c8 = rem & 3;
      int g = c8 ^ ((px >> 1) & 3);
      async16(A + ((size_t)(b * HP_ + h0 + ry) * WP_ + (w0 + px)) * 128 + ci0 + g * 8,
              As + i * 8);
    }
    __syncthreads();
#pragma unroll
    for (int tap = 0; tap < 9; ++tap) {
      const int ky = tap / 3, kx = tap % 3;
      bf16x8 bw = *(const bf16x8*)&Wf[(size_t)(((tap * 4 + cq) * 4 + kq) * 16 + lr) * 8];
      bf16x8 af[4];
#pragma unroll
      for (int i = 0; i < 4; ++i)
        af[i] = *(const bf16x8*)&As[(wave + ky) * ROWU + preA[i][kx]];
#pragma unroll
      for (int i = 0; i < 4; i++)
        acc[i] = __builtin_amdgcn_mfma_f32_16x16x32_bf16(af[i], bw, acc[i], 0, 0, 0);
    }
  }

  __syncthreads();  // staging region dead; reuse as off_lds
#pragma unroll
  for (int i = 0; i < 4; i++) {
#pragma unroll
    for (int r = 0; r < 4; r++) {
      if (lr < 8) {
        int px = i * 16 + (lane >> 4) * 4 + r;
        off_lds[(wave * 64 + px) * 9 + lr] = acc[i][r] + bias[lr];
      }
    }
  }
  __syncthreads();

  // one pixel per thread
  const int pp = tid;
  const int h = h0 + (pp >> 6), w = w0 + (pp & 63);
  const int pix = b * P_ + h * W_ + w;
  const u16* wp = w1b + (size_t)pix * 32;
  float f[32];
#pragma unroll
  for (int i = 0; i < 32; i += 2) {
    unsigned u = *(const unsigned*)&wp[i];
    f[i] = bf2f((u16)u); f[i + 1] = bf2f((u16)(u >> 16));
  }
  float lg[4];
#pragma unroll
  for (int k = 0; k < 4; k++) {
    float sacc = wb2[k];
#pragma unroll
    for (int i = 0; i < 32; i++) sacc = fmaf(ww2[k * 32 + i], f[i], sacc);
    lg[k] = sacc;
  }
  float mx = fmaxf(fmaxf(lg[0], lg[1]), fmaxf(lg[2], lg[3]));
  float e[4], sum = 0.f;
#pragma unroll
  for (int k = 0; k < 4; k++) { e[k] = __expf(lg[k] - mx); sum += e[k]; }
  const float inv = 1.0f / sum;
#pragma unroll
  for (int k = 0; k < 4; k++) {
    float ox = off_lds[pp * 9 + 2 * k], oy = off_lds[pp * 9 + 2 * k + 1];
    float gx = (2.0f * w / 255.0f - 1.0f) + ox * (1.0f / 128.0f);
    float gy = (2.0f * h / 255.0f - 1.0f) + oy * (1.0f / 128.0f);
    gx = fminf(fmaxf(gx, -1.f), 1.f);
    gy = fminf(fmaxf(gy, -1.f), 1.f);
    float px = fminf(fmaxf((gx + 1.f) * 127.5f, 0.f), 255.f);
    float py = fminf(fmaxf((gy + 1.f) * 127.5f, 0.f), 255.f);
    int x0 = (int)px, y0 = (int)py;
    int x1 = min(x0 + 1, 255), y1 = min(y0 + 1, 255);
    float wx = px - x0, wy = py - y0;
    float wk = e[k] * inv;
    float w00 = (1.f - wx) * (1.f - wy) * wk, w01 = wx * (1.f - wy) * wk;
    float w10 = (1.f - wx) * wy * wk,         w11 = wx * wy * wk;
    HU t01, t23;
    t01.h = __floats2half2_rn(w00, w01);
    t23.h = __floats2half2_rn(w10, w11);
    uint4 d;
    d.x = (unsigned)(y0 * 256 + x0) | ((unsigned)(x1 - x0) << 16) | ((unsigned)(y1 - y0) << 17);
    d.y = t01.u; d.z = t23.u; d.w = 0;
    desc[(size_t)pix * 4 + k] = d;
  }
}

// ---------------- sampler: wave per pixel, lane = channel pair ------------------------
__global__ __launch_bounds__(256) void sampler(
    const uint4* __restrict__ desc, const u16* __restrict__ keyn, u16* __restrict__ agg) {
  const int tid = threadIdx.x, lane = tid & 63, wv = tid >> 6;
  const int pix = blockIdx.x * 4 + wv;
  const int b = pix >> 16;
  const u16* kb = keyn + (size_t)b * (P_ * C_) + 2 * lane;
  float a0 = 0.f, a1 = 0.f;
#pragma unroll
  for (int k = 0; k < 4; ++k) {
    uint4 d = desc[(size_t)pix * 4 + k];
    const int boff = (int)(d.x & 0xFFFFu) << 7;
    const int o01 = (int)((d.x >> 16) & 1u) << 7;
    const int o10 = (int)((d.x >> 17) & 1u) << 15;
    const u16* c0 = kb + boff;
    unsigned u00 = *(const unsigned*)(c0);
    unsigned u01 = *(const unsigned*)(c0 + o01);
    unsigned u10 = *(const unsigned*)(c0 + o10);
    unsigned u11 = *(const unsigned*)(c0 + o10 + o01);
    HU t01, t23; t01.u = d.y; t23.u = d.z;
    float2 wA = __half22float2(t01.h);
    float2 wB = __half22float2(t23.h);
    a0 = fmaf(wA.x, bf2f((u16)u00), a0);
    a0 = fmaf(wA.y, bf2f((u16)u01), a0);
    a0 = fmaf(wB.x, bf2f((u16)u10), a0);
    a0 = fmaf(wB.y, bf2f((u16)u11), a0);
    a1 = fmaf(wA.x, bf2f((u16)(u00 >> 16)), a1);
    a1 = fmaf(wA.y, bf2f((u16)(u01 >> 16)), a1);
    a1 = fmaf(wB.x, bf2f((u16)(u10 >> 16)), a1);
    a1 = fmaf(wB.y, bf2f((u16)(u11 >> 16)), a1);
  }
  unsigned outu = ((unsigned)f2bf(a1) << 16) | (unsigned)f2bf(a0);
  *(unsigned*)&agg[(size_t)pix * C_ + 2 * lane] = outu;
}

// ---------------- fused fusion: 1x1 conv + GELU -> LDS -> 1x1 conv + residual ---------
// 512 threads = 8 waves; per-wave 2x4 acc tiles (32 AGPR) -> 4 waves/SIMD occupancy.
// block = 128 px x 128 co (all of K for GEMM2 is produced in-block).
__global__ __launch_bounds__(512, 4) void conv_fuse(
    const u16* __restrict__ Aagg, const u16* __restrict__ W1, const u16* __restrict__ W2,
    const float* __restrict__ b1, const float* __restrict__ b2,
    const float* __restrict__ resid, float* __restrict__ out) {
  __shared__ __align__(16) u16 SM[16384];   // phase1: As[0:8192) Bs[8192:16384); phase2: Bs2
  __shared__ __align__(16) u16 T2[128 * 136];  // GELU tile, px pitch 136 u16 (272B)
  u16* As = SM;
  u16* Bs = SM + 8192;
  const int tid = threadIdx.x, lane = tid & 63, wave = tid >> 6;  // 8 waves
  const int h = blockIdx.y, w0 = blockIdx.x * 128;
  const int b = blockIdx.z;
  const int wr = wave >> 1, wc = wave & 1;
  const int wm = wr * 32, wn = wc * 64;
  const int lr = lane & 15, kq = lane >> 4;
  const int sw = lr & 7;

  f32x4 acc[2][4];
#pragma unroll
  for (int i = 0; i < 2; i++)
#pragma unroll
    for (int j = 0; j < 4; j++) { f32x4 z = {0.f, 0.f, 0.f, 0.f}; acc[i][j] = z; }

  // ---- GEMM1: agg(128px x 128ci) @ fw1 -> acc
  for (int c = 0; c < 2; ++c) {
    const int ci0 = c << 6;
    const u16* Ab = Aagg + (((size_t)b * H_ + h) * W_ + w0) * 128 + ci0;
    const u16* Wb = W1 + ci0;
    __syncthreads();
    for (int i = tid; i < 128 * 8; i += 512) {
      int r = i >> 3, cb = i & 7;
      async16(Ab + r * 128 + ((cb ^ (r & 7)) << 3), As + i * 8);
    }
    for (int i = tid; i < 128 * 8; i += 512) {
      int r = i >> 3, cb = i & 7;
      async16(Wb + r * 128 + ((cb ^ (r & 7)) << 3), Bs + i * 8);
    }
    __syncthreads();
#pragma unroll
    for (int ks = 0; ks < 2; ++ks) {
      const int kb = ks * 4 + kq;
      bf16x8 af[2], bfr[4];
#pragma unroll
      for (int i = 0; i < 2; i++)
        af[i] = *(const bf16x8*)&As[(wm + i * 16 + lr) * 64 + ((kb ^ sw) << 3)];
#pragma unroll
      for (int j = 0; j < 4; j++)
        bfr[j] = *(const bf16x8*)&Bs[(wn + j * 16 + lr) * 64 + ((kb ^ sw) << 3)];
#pragma unroll
      for (int i = 0; i < 2; i++)
#pragma unroll
        for (int j = 0; j < 4; j++)
          acc[i][j] = __builtin_amdgcn_mfma_f32_16x16x32_bf16(af[i], bfr[j], acc[i][j], 0, 0, 0);
    }
  }

  // ---- GELU -> T2 (bf16), then stage fw2 into SM
#pragma unroll
  for (int i = 0; i < 2; i++)
#pragma unroll
    for (int j = 0; j < 4; j++) {
      const int co = wn + j * 16 + lr;
#pragma unroll
      for (int r = 0; r < 4; r++) {
        const int px = wm + i * 16 + kq * 4 + r;
        T2[px * 136 + co] = f2bf(gelu_f(acc[i][j][r] + b1[co]));
      }
    }
  __syncthreads();
  for (int i = tid; i < 2048; i += 512) {   // 128co x 16 chunks
    int r = i >> 4, sl = i & 15;
    int g = sl ^ (r & 7);
    async16(W2 + r * 128 + g * 8, SM + i * 8);
  }
  __syncthreads();

  // ---- GEMM2: T2(128px x 128k) @ fw2 -> acc
#pragma unroll
  for (int i = 0; i < 2; i++)
#pragma unroll
    for (int j = 0; j < 4; j++) { f32x4 z = {0.f, 0.f, 0.f, 0.f}; acc[i][j] = z; }
#pragma unroll
  for (int ks = 0; ks < 4; ++ks) {
    const int kc = ks * 4 + kq;
    bf16x8 af[2], bfr[4];
#pragma unroll
    for (int i = 0; i < 2; i++)
      af[i] = *(const bf16x8*)&T2[(wm + i * 16 + lr) * 136 + kc * 8];
#pragma unroll
    for (int j = 0; j < 4; j++) {
      int rr = wn + j * 16 + lr;
      bfr[j] = *(const bf16x8*)&SM[rr * 128 + (kc ^ (rr & 7)) * 8];
    }
#pragma unroll
    for (int i = 0; i < 2; i++)
#pragma unroll
      for (int j = 0; j < 4; j++)
        acc[i][j] = __builtin_amdgcn_mfma_f32_16x16x32_bf16(af[i], bfr[j], acc[i][j], 0, 0, 0);
  }

  // ---- residual epilogue (fp32 NCHW)
#pragma unroll
  for (int i = 0; i < 2; i++) {
#pragma unroll
    for (int j = 0; j < 4; j++) {
      const int co = wn + j * 16 + lr;
      const int w = w0 + wm + i * 16 + kq * 4;
      size_t idx = ((size_t)b * 128 + co) * (size_t)P_ + (size_t)h * W_ + w;
      float4 rv = *(const float4*)&resid[idx];
      float bi = b2[co];
      float4 ov;
      ov.x = rv.x + 0.3f * (acc[i][j][0] + bi);
      ov.y = rv.y + 0.3f * (acc[i][j][1] + bi);
      ov.z = rv.z + 0.3f * (acc[i][j][2] + bi);
      ov.w = rv.w + 0.3f * (acc[i][j][3] + bi);
      *(float4*)&out[idx] = ov;
    }
  }
}

extern "C" void kernel_launch(void* const* d_in, const int* in_sizes, int n_in,
                              void* d_out, int out_size, void* d_ws, size_t ws_size,
                              hipStream_t stream) {
  (void)in_sizes; (void)n_in; (void)out_size; (void)ws_size;
  const float* q   = (const float*)d_in[0];
  const float* key = (const float*)d_in[1];
  const float* ow1 = (const float*)d_in[2];
  const float* ob1 = (const float*)d_in[3];
  const float* ow2 = (const float*)d_in[4];
  const float* ob2 = (const float*)d_in[5];
  const float* ww1 = (const float*)d_in[6];
  const float* wb1 = (const float*)d_in[7];
  const float* ww2 = (const float*)d_in[8];
  const float* wb2 = (const float*)d_in[9];
  const float* fw1 = (const float*)d_in[10];
  const float* fb1 = (const float*)d_in[11];
  const float* fw2 = (const float*)d_in[12];
  const float* fb2 = (const float*)d_in[13];
  float* out = (float*)d_out;
  char* ws = (char*)d_ws;

  // workspace: qpad @0 (34.08MB, reused as desc after conv3_big); t1pad @34080768
  // (34.08MB, reused as agg); keyn @68161536 (33.55MB); w1b @101715968 (8.39MB);
  // wbuf @110104576 (471KB). peak 110.6MB.
  u16* qpad  = (u16*)(ws);
  u16* t1pad = (u16*)(ws + 34080768);
  u16* keyn  = (u16*)(ws + 68161536);
  u16* w1b   = (u16*)(ws + 101715968);
  u16* wbuf  = (u16*)(ws + 110104576);
  uint4* desc = (uint4*)ws;        // qpad dead after conv3_big
  u16* agg = t1pad;                // t1pad dead after conv_off

  prologue<<<11176, 256, 0, stream>>>(q, key, ow1, ow2, ww1, fw1, fw2,
                                      qpad, keyn, t1pad, wbuf);
  conv3_big<<<1024, 512, 0, stream>>>(qpad, wbuf, ob1, wb1, t1pad, w1b);
  conv_off<<<512, 256, 0, stream>>>(t1pad, wbuf + 184320, ob2, w1b, ww2, wb2, desc);
  sampler<<<32768, 256, 0, stream>>>(desc, keyn, agg);
  conv_fuse<<<dim3(2, 256, 2), 512, 0, stream>>>(agg, wbuf + 202752, wbuf + 219136,
                                                 fb1, fb2, q, out);
}

// Round 8
// 357.011 us; speedup vs baseline: 1.0437x; 1.0437x over previous
//
#include <hip/hip_runtime.h>
#include <hip/hip_fp16.h>

typedef unsigned short u16;
typedef __attribute__((ext_vector_type(8))) short bf16x8;
typedef __attribute__((ext_vector_type(4))) float f32x4;

constexpr int B_ = 2, C_ = 128, H_ = 256, W_ = 256, P_ = H_ * W_;
constexpr int HP_ = 258, WP_ = 258;

union HU { __half2 h; unsigned int u; };

__device__ __forceinline__ float bf2f(u16 u) {
  union { unsigned int i; float f; } v; v.i = ((unsigned int)u) << 16; return v.f;
}
__device__ __forceinline__ u16 f2bf(float f) {
  union { float f; unsigned int i; } v; v.f = f;
  return (u16)((v.i + 0x7fffu + ((v.i >> 16) & 1u)) >> 16);  // RNE
}
// tanh-form GELU via sigmoid; |dev from erf-GELU| <= ~5e-4
__device__ __forceinline__ float gelu_f(float x) {
  float u = x * (1.5957691216057308f + 0.071354816272f * x * x);
  return x / (1.0f + __expf(-u));
}

// async global->LDS, 16B per lane. LDS dest must be wave-uniform base + lane*16.
__device__ __forceinline__ void async16(const u16* g, u16* l) {
  __builtin_amdgcn_global_load_lds(
      (const __attribute__((address_space(1))) unsigned int*)g,
      (__attribute__((address_space(3))) unsigned int*)l, 16, 0, 0);
}

// ---------------- prologue: to_nhwc(q), to_nhwc(key), border-zero x2, repack ----------
// grid: [0,8192) nhwc transposes; [8192,10256) border; [10256,11176) repack
// NHWC transpose loads vectorized to float4 (G13): 4 iters x 16B/lane instead of
// 16 iters x 4B/lane. LDS tile layout and store loop unchanged.
__global__ __launch_bounds__(256) void prologue(
    const float* __restrict__ q, const float* __restrict__ key,
    const float* __restrict__ ow1, const float* __restrict__ ow2,
    const float* __restrict__ ww1, const float* __restrict__ fw1,
    const float* __restrict__ fw2,
    u16* __restrict__ qpad, u16* __restrict__ keyn, u16* __restrict__ t1pad,
    u16* __restrict__ wb) {
  __shared__ u16 l[64 * 66];
  const int id = blockIdx.x, tid = threadIdx.x;
  if (id < 8192) {
    int z = id >> 10, r = id & 1023;
    int bx = r & 3, by = r >> 2;
    const float* in; u16* out; int OW, opad;
    if (z < 4) { in = q; out = qpad; OW = WP_; opad = 1; }
    else { z -= 4; in = key; out = keyn; OW = W_; opad = 0; }
    int b = z >> 1, c0 = (z & 1) * 64;
    int h = by, w0 = bx * 64;
    for (int it = 0; it < 4; ++it) {
      int lin = it * 256 + tid;                 // 1024 float4 quads
      int c = lin >> 4, w4 = (lin & 15) * 4;
      float4 v = *(const float4*)&in[(((size_t)b * C_ + c0 + c) * H_ + h) * W_ + w0 + w4];
      l[c * 66 + w4 + 0] = f2bf(v.x);
      l[c * 66 + w4 + 1] = f2bf(v.y);
      l[c * 66 + w4 + 2] = f2bf(v.z);
      l[c * 66 + w4 + 3] = f2bf(v.w);
    }
    __syncthreads();
    int OH = (opad ? HP_ : H_);
    for (int it = 0; it < 16; ++it) {
      int lin = it * 256 + tid;
      int w = lin >> 6, c = lin & 63;
      out[(((size_t)b * OH + h + opad) * OW + (w0 + w + opad)) * C_ + c0 + c] = l[c * 66 + w];
    }
  } else if (id < 10256) {
    int j = id - 8192;
    u16* buf = (j < 1032) ? qpad : t1pad;
    int idx = ((j < 1032) ? j : j - 1032) * 256 + tid;
    int c = idx & 127;
    int t = idx >> 7;
    int pos = t % 258;
    int side = (t / 258) & 3;
    int b = t / (258 * 4);
    int h, w;
    if (side == 0) { h = 0; w = pos; }
    else if (side == 1) { h = 257; w = pos; }
    else if (side == 2) { h = pos; w = 0; }
    else { h = pos; w = 257; }
    buf[(((size_t)b * HP_ + h) * WP_ + w) * C_ + c] = 0;
  } else {
    // repack weights into wbuf (bf16):
    // W1c @0: ow1+ww1 fragment-packed [tap][cq][g 10][kb 4][lr 16][e 8] = 184320
    // W2 @184320: ow2 packed GT=1, co 8->16 zero-pad = 18432
    // fw1 @202752 row-major [co][ci] 16384 ; fw2 @219136 row-major 16384
    int idx = (id - 10256) * 256 + tid;
    float v;
    if (idx < 184320) {
      int e = idx & 7, lr = (idx >> 3) & 15, kb = (idx >> 7) & 3;
      int t = idx >> 9;
      int g = t % 10, u = t / 10;
      int cq = u & 3, tap = u >> 2;
      int ci = cq * 32 + kb * 8 + e, co = g * 16 + lr;
      v = (co < 128) ? ow1[(co * 128 + ci) * 9 + tap]
                     : ww1[((co - 128) * 128 + ci) * 9 + tap];
    } else if (idx < 202752) {
      int j = idx - 184320;
      int e = j & 7, lr = (j >> 3) & 15, kb = (j >> 7) & 3;
      int cq = (j >> 9) & 3, tap = j >> 11;
      int ci = cq * 32 + kb * 8 + e, co = lr;
      v = (co < 8) ? ow2[(co * 128 + ci) * 9 + tap] : 0.0f;
    } else if (idx < 219136) {
      v = fw1[idx - 202752];
    } else {
      v = fw2[idx - 219136];
    }
    wb[idx] = f2bf(v);
  }
}

// ---------------- combined 3x3 conv (ow1 128->128 + ww1 128->32), band-tiled ----------
// R0-measured structure (74.5 us best): single As buffer, serial stage per ci-quarter,
// weights read directly from global per tap. R2 dbuf (+3 us) and R7 reg-prefetch
// (+13 us, 2x HBM traffic from disrupted write-combining) both REGRESSED — reverted.
__global__ __launch_bounds__(512, 4) void conv3_big(
    const u16* __restrict__ A, const u16* __restrict__ Wf,
    const float* __restrict__ bias1, const float* __restrict__ bias2,
    u16* __restrict__ outb, u16* __restrict__ outw) {
  constexpr int RPX = 36, ROWU = RPX * 32;          // u16 per row-plane = 1152
  __shared__ __align__(16) u16 As[6 * ROWU];        // 13,824 B
  const int tid = threadIdx.x, lane = tid & 63, wave = tid >> 6;  // 8 waves
  const int id = blockIdx.x;
  const int s = id >> 3;
  const int h0 = (((id & 7) << 3) | (s & 7)) << 2;  // 4-row band
  const int w0 = ((s >> 3) & 7) << 5;
  const int b = s >> 6;
  const int wr = wave >> 1, wc = wave & 1;          // wr: row 0..3, wc: co half
  const int wn = wc * 80;
  const int lr = lane & 15, kq = lane >> 4;
  const int gbase = wn >> 4;                        // 0 or 5

  int preA[2][3];
#pragma unroll
  for (int i = 0; i < 2; i++)
#pragma unroll
    for (int kx = 0; kx < 3; kx++) {
      int pxv = i * 16 + lr + kx;
      preA[i][kx] = (pxv * 4 + (kq ^ ((pxv >> 1) & 3))) * 8;  // u16 units
    }

  f32x4 acc[2][5];
#pragma unroll
  for (int i = 0; i < 2; i++)
#pragma unroll
    for (int j = 0; j < 5; j++) { f32x4 z = {0.f, 0.f, 0.f, 0.f}; acc[i][j] = z; }

  for (int cq = 0; cq < 4; ++cq) {
    const int ci0 = cq * 32;
    __syncthreads();
    for (int i = tid; i < 864; i += 512) {
      int ry = i / 144;
      int rem = i - ry * 144;
      int px = rem >> 2, c8 = rem & 3;
      int g = c8 ^ ((px >> 1) & 3);
      async16(A + ((size_t)(b * HP_ + h0 + ry) * WP_ + (w0 + px)) * 128 + ci0 + g * 8,
              As + i * 8);
    }
    __syncthreads();
#pragma unroll
    for (int tap = 0; tap < 9; ++tap) {
      const int ky = tap / 3, kx = tap % 3;
      bf16x8 bfr[5], af[2];
#pragma unroll
      for (int j = 0; j < 5; ++j)
        bfr[j] = *(const bf16x8*)&Wf[(size_t)((((tap * 4 + cq) * 10 + gbase + j) * 4 + kq) * 16 + lr) * 8];
#pragma unroll
      for (int i = 0; i < 2; ++i)
        af[i] = *(const bf16x8*)&As[(wr + ky) * ROWU + preA[i][kx]];
#pragma unroll
      for (int i = 0; i < 2; i++)
#pragma unroll
        for (int j = 0; j < 5; j++)
          acc[i][j] = __builtin_amdgcn_mfma_f32_16x16x32_bf16(af[i], bfr[j], acc[i][j], 0, 0, 0);
    }
  }

  const int h = h0 + wr;
#pragma unroll
  for (int i = 0; i < 2; i++) {
#pragma unroll
    for (int j = 0; j < 5; j++) {
      const int co = wn + j * 16 + lr;
#pragma unroll
      for (int r = 0; r < 4; r++) {
        const int w = w0 + i * 16 + kq * 4 + r;
        float v = acc[i][j][r];
        if (co < 128) {
          v = gelu_f(v + bias1[co]);
          outb[(((size_t)b * HP_ + h + 1) * WP_ + (w + 1)) * 128 + co] = f2bf(v);
        } else {
          v = gelu_f(v + bias2[co - 128]);
          outw[((size_t)b * P_ + (size_t)h * W_ + w) * 32 + (co - 128)] = f2bf(v);
        }
      }
    }
  }
}

// ---------------- offsets conv (3x3 128->8) + fused prep epilogue ---------------------
// BM=256 as 4 rows x 64 px; BN=16; wave = one row. Epilogue: offs->LDS regroup,
// then per-thread pixel: logits(32->4), softmax, grid math -> desc.
__global__ __launch_bounds__(256) void conv_off(
    const u16* __restrict__ A, const u16* __restrict__ Wf,
    const float* __restrict__ bias,
    const u16* __restrict__ w1b, const float* __restrict__ ww2,
    const float* __restrict__ wb2, uint4* __restrict__ desc) {
  constexpr int RPX = 66, ROWU = RPX * 32;          // 2112 u16 per row-plane
  __shared__ __align__(16) u16 As[6 * ROWU];        // 25,344 B
  float* off_lds = (float*)As;                      // reused after K-loop (256*9*4 B)
  const int tid = threadIdx.x, lane = tid & 63, wave = tid >> 6;
  const int id = blockIdx.x;
  const int s = id >> 3;
  const int h0 = (((id & 7) << 3) | (s & 7)) << 2;
  const int w0 = ((s >> 3) & 3) << 6;
  const int b = s >> 5;
  const int lr = lane & 15, kq = lane >> 4;

  int preA[4][3];
#pragma unroll
  for (int i = 0; i < 4; i++)
#pragma unroll
    for (int kx = 0; kx < 3; kx++) {
      int pxv = i * 16 + lr + kx;
      preA[i][kx] = (pxv * 4 + (kq ^ ((pxv >> 1) & 3))) * 8;
    }

  f32x4 acc[4];
#pragma unroll
  for (int i = 0; i < 4; i++) { f32x4 z = {0.f, 0.f, 0.f, 0.f}; acc[i] = z; }

  for (int cq = 0; cq < 4; ++cq) {
    const int ci0 = cq * 32;
    __syncthreads();
    for (int i = tid; i < 1584; i += 256) {
      int ry = i / 264;
      int rem = i - ry * 264;
      int px = rem >> 2, c8 = rem & 3;
      int g = c8 ^ ((px >> 1) & 3);
      async16(A + ((size_t)(b * HP_ + h0 + ry) * WP_ + (w0 + px)) * 128 + ci0 + g * 8,
              As + i * 8);
    }
    __syncthreads();
#pragma unroll
    for (int tap = 0; tap < 9; ++tap) {
      const int ky = tap / 3, kx = tap % 3;
      bf16x8 bw = *(const bf16x8*)&Wf[(size_t)(((tap * 4 + cq) * 4 + kq) * 16 + lr) * 8];
      bf16x8 af[4];
#pragma unroll
      for (int i = 0; i < 4; ++i)
        af[i] = *(const bf16x8*)&As[(wave + ky) * ROWU + preA[i][kx]];
#pragma unroll
      for (int i = 0; i < 4; i++)
        acc[i] = __builtin_amdgcn_mfma_f32_16x16x32_bf16(af[i], bw, acc[i], 0, 0, 0);
    }
  }

  __syncthreads();  // staging region dead; reuse as off_lds
#pragma unroll
  for (int i = 0; i < 4; i++) {
#pragma unroll
    for (int r = 0; r < 4; r++) {
      if (lr < 8) {
        int px = i * 16 + (lane >> 4) * 4 + r;
        off_lds[(wave * 64 + px) * 9 + lr] = acc[i][r] + bias[lr];
      }
    }
  }
  __syncthreads();

  // one pixel per thread
  const int pp = tid;
  const int h = h0 + (pp >> 6), w = w0 + (pp & 63);
  const int pix = b * P_ + h * W_ + w;
  const u16* wp = w1b + (size_t)pix * 32;
  float f[32];
#pragma unroll
  for (int i = 0; i < 32; i += 2) {
    unsigned u = *(const unsigned*)&wp[i];
    f[i] = bf2f((u16)u); f[i + 1] = bf2f((u16)(u >> 16));
  }
  float lg[4];
#pragma unroll
  for (int k = 0; k < 4; k++) {
    float sacc = wb2[k];
#pragma unroll
    for (int i = 0; i < 32; i++) sacc = fmaf(ww2[k * 32 + i], f[i], sacc);
    lg[k] = sacc;
  }
  float mx = fmaxf(fmaxf(lg[0], lg[1]), fmaxf(lg[2], lg[3]));
  float e[4], sum = 0.f;
#pragma unroll
  for (int k = 0; k < 4; k++) { e[k] = __expf(lg[k] - mx); sum += e[k]; }
  const float inv = 1.0f / sum;
#pragma unroll
  for (int k = 0; k < 4; k++) {
    float ox = off_lds[pp * 9 + 2 * k], oy = off_lds[pp * 9 + 2 * k + 1];
    float gx = (2.0f * w / 255.0f - 1.0f) + ox * (1.0f / 128.0f);
    float gy = (2.0f * h / 255.0f - 1.0f) + oy * (1.0f / 128.0f);
    gx = fminf(fmaxf(gx, -1.f), 1.f);
    gy = fminf(fmaxf(gy, -1.f), 1.f);
    float px = fminf(fmaxf((gx + 1.f) * 127.5f, 0.f), 255.f);
    float py = fminf(fmaxf((gy + 1.f) * 127.5f, 0.f), 255.f);
    int x0 = (int)px, y0 = (int)py;
    int x1 = min(x0 + 1, 255), y1 = min(y0 + 1, 255);
    float wx = px - x0, wy = py - y0;
    float wk = e[k] * inv;
    float w00 = (1.f - wx) * (1.f - wy) * wk, w01 = wx * (1.f - wy) * wk;
    float w10 = (1.f - wx) * wy * wk,         w11 = wx * wy * wk;
    HU t01, t23;
    t01.h = __floats2half2_rn(w00, w01);
    t23.h = __floats2half2_rn(w10, w11);
    uint4 d;
    d.x = (unsigned)(y0 * 256 + x0) | ((unsigned)(x1 - x0) << 16) | ((unsigned)(y1 - y0) << 17);
    d.y = t01.u; d.z = t23.u; d.w = 0;
    desc[(size_t)pix * 4 + k] = d;
  }
}

// ---------------- sampler: wave per pixel, lane = channel pair ------------------------
__global__ __launch_bounds__(256) void sampler(
    const uint4* __restrict__ desc, const u16* __restrict__ keyn, u16* __restrict__ agg) {
  const int tid = threadIdx.x, lane = tid & 63, wv = tid >> 6;
  const int pix = blockIdx.x * 4 + wv;
  const int b = pix >> 16;
  const u16* kb = keyn + (size_t)b * (P_ * C_) + 2 * lane;
  float a0 = 0.f, a1 = 0.f;
#pragma unroll
  for (int k = 0; k < 4; ++k) {
    uint4 d = desc[(size_t)pix * 4 + k];
    const int boff = (int)(d.x & 0xFFFFu) << 7;
    const int o01 = (int)((d.x >> 16) & 1u) << 7;
    const int o10 = (int)((d.x >> 17) & 1u) << 15;
    const u16* c0 = kb + boff;
    unsigned u00 = *(const unsigned*)(c0);
    unsigned u01 = *(const unsigned*)(c0 + o01);
    unsigned u10 = *(const unsigned*)(c0 + o10);
    unsigned u11 = *(const unsigned*)(c0 + o10 + o01);
    HU t01, t23; t01.u = d.y; t23.u = d.z;
    float2 wA = __half22float2(t01.h);
    float2 wB = __half22float2(t23.h);
    a0 = fmaf(wA.x, bf2f((u16)u00), a0);
    a0 = fmaf(wA.y, bf2f((u16)u01), a0);
    a0 = fmaf(wB.x, bf2f((u16)u10), a0);
    a0 = fmaf(wB.y, bf2f((u16)u11), a0);
    a1 = fmaf(wA.x, bf2f((u16)(u00 >> 16)), a1);
    a1 = fmaf(wA.y, bf2f((u16)(u01 >> 16)), a1);
    a1 = fmaf(wB.x, bf2f((u16)(u10 >> 16)), a1);
    a1 = fmaf(wB.y, bf2f((u16)(u11 >> 16)), a1);
  }
  unsigned outu = ((unsigned)f2bf(a1) << 16) | (unsigned)f2bf(a0);
  *(unsigned*)&agg[(size_t)pix * C_ + 2 * lane] = outu;
}

// ---------------- fused fusion: 1x1 conv + GELU -> LDS -> 1x1 conv + residual ---------
// 512 threads = 8 waves; per-wave 2x4 acc tiles (32 AGPR) -> 4 waves/SIMD occupancy.
// block = 128 px x 128 co (all of K for GEMM2 is produced in-block).
__global__ __launch_bounds__(512, 4) void conv_fuse(
    const u16* __restrict__ Aagg, const u16* __restrict__ W1, const u16* __restrict__ W2,
    const float* __restrict__ b1, const float* __restrict__ b2,
    const float* __restrict__ resid, float* __restrict__ out) {
  __shared__ __align__(16) u16 SM[16384];   // phase1: As[0:8192) Bs[8192:16384); phase2: Bs2
  __shared__ __align__(16) u16 T2[128 * 136];  // GELU tile, px pitch 136 u16 (272B)
  u16* As = SM;
  u16* Bs = SM + 8192;
  const int tid = threadIdx.x, lane = tid & 63, wave = tid >> 6;  // 8 waves
  const int h = blockIdx.y, w0 = blockIdx.x * 128;
  const int b = blockIdx.z;
  const int wr = wave >> 1, wc = wave & 1;
  const int wm = wr * 32, wn = wc * 64;
  const int lr = lane & 15, kq = lane >> 4;
  const int sw = lr & 7;

  f32x4 acc[2][4];
#pragma unroll
  for (int i = 0; i < 2; i++)
#pragma unroll
    for (int j = 0; j < 4; j++) { f32x4 z = {0.f, 0.f, 0.f, 0.f}; acc[i][j] = z; }

  // ---- GEMM1: agg(128px x 128ci) @ fw1 -> acc
  for (int c = 0; c < 2; ++c) {
    const int ci0 = c << 6;
    const u16* Ab = Aagg + (((size_t)b * H_ + h) * W_ + w0) * 128 + ci0;
    const u16* Wb = W1 + ci0;
    __syncthreads();
    for (int i = tid; i < 128 * 8; i += 512) {
      int r = i >> 3, cb = i & 7;
      async16(Ab + r * 128 + ((cb ^ (r & 7)) << 3), As + i * 8);
    }
    for (int i = tid; i < 128 * 8; i += 512) {
      int r = i >> 3, cb = i & 7;
      async16(Wb + r * 128 + ((cb ^ (r & 7)) << 3), Bs + i * 8);
    }
    __syncthreads();
#pragma unroll
    for (int ks = 0; ks < 2; ++ks) {
      const int kb = ks * 4 + kq;
      bf16x8 af[2], bfr[4];
#pragma unroll
      for (int i = 0; i < 2; i++)
        af[i] = *(const bf16x8*)&As[(wm + i * 16 + lr) * 64 + ((kb ^ sw) << 3)];
#pragma unroll
      for (int j = 0; j < 4; j++)
        bfr[j] = *(const bf16x8*)&Bs[(wn + j * 16 + lr) * 64 + ((kb ^ sw) << 3)];
#pragma unroll
      for (int i = 0; i < 2; i++)
#pragma unroll
        for (int j = 0; j < 4; j++)
          acc[i][j] = __builtin_amdgcn_mfma_f32_16x16x32_bf16(af[i], bfr[j], acc[i][j], 0, 0, 0);
    }
  }

  // ---- GELU -> T2 (bf16), then stage fw2 into SM
#pragma unroll
  for (int i = 0; i < 2; i++)
#pragma unroll
    for (int j = 0; j < 4; j++) {
      const int co = wn + j * 16 + lr;
#pragma unroll
      for (int r = 0; r < 4; r++) {
        const int px = wm + i * 16 + kq * 4 + r;
        T2[px * 136 + co] = f2bf(gelu_f(acc[i][j][r] + b1[co]));
      }
    }
  __syncthreads();
  for (int i = tid; i < 2048; i += 512) {   // 128co x 16 chunks
    int r = i >> 4, sl = i & 15;
    int g = sl ^ (r & 7);
    async16(W2 + r * 128 + g * 8, SM + i * 8);
  }
  __syncthreads();

  // ---- GEMM2: T2(128px x 128k) @ fw2 -> acc
#pragma unroll
  for (int i = 0; i < 2; i++)
#pragma unroll
    for (int j = 0; j < 4; j++) { f32x4 z = {0.f, 0.f, 0.f, 0.f}; acc[i][j] = z; }
#pragma unroll
  for (int ks = 0; ks < 4; ++ks) {
    const int kc = ks * 4 + kq;
    bf16x8 af[2], bfr[4];
#pragma unroll
    for (int i = 0; i < 2; i++)
      af[i] = *(const bf16x8*)&T2[(wm + i * 16 + lr) * 136 + kc * 8];
#pragma unroll
    for (int j = 0; j < 4; j++) {
      int rr = wn + j * 16 + lr;
      bfr[j] = *(const bf16x8*)&SM[rr * 128 + (kc ^ (rr & 7)) * 8];
    }
#pragma unroll
    for (int i = 0; i < 2; i++)
#pragma unroll
      for (int j = 0; j < 4; j++)
        acc[i][j] = __builtin_amdgcn_mfma_f32_16x16x32_bf16(af[i], bfr[j], acc[i][j], 0, 0, 0);
  }

  // ---- residual epilogue (fp32 NCHW)
#pragma unroll
  for (int i = 0; i < 2; i++) {
#pragma unroll
    for (int j = 0; j < 4; j++) {
      const int co = wn + j * 16 + lr;
      const int w = w0 + wm + i * 16 + kq * 4;
      size_t idx = ((size_t)b * 128 + co) * (size_t)P_ + (size_t)h * W_ + w;
      float4 rv = *(const float4*)&resid[idx];
      float bi = b2[co];
      float4 ov;
      ov.x = rv.x + 0.3f * (acc[i][j][0] + bi);
      ov.y = rv.y + 0.3f * (acc[i][j][1] + bi);
      ov.z = rv.z + 0.3f * (acc[i][j][2] + bi);
      ov.w = rv.w + 0.3f * (acc[i][j][3] + bi);
      *(float4*)&out[idx] = ov;
    }
  }
}

extern "C" void kernel_launch(void* const* d_in, const int* in_sizes, int n_in,
                              void* d_out, int out_size, void* d_ws, size_t ws_size,
                              hipStream_t stream) {
  (void)in_sizes; (void)n_in; (void)out_size; (void)ws_size;
  const float* q   = (const float*)d_in[0];
  const float* key = (const float*)d_in[1];
  const float* ow1 = (const float*)d_in[2];
  const float* ob1 = (const float*)d_in[3];
  const float* ow2 = (const float*)d_in[4];
  const float* ob2 = (const float*)d_in[5];
  const float* ww1 = (const float*)d_in[6];
  const float* wb1 = (const float*)d_in[7];
  const float* ww2 = (const float*)d_in[8];
  const float* wb2 = (const float*)d_in[9];
  const float* fw1 = (const float*)d_in[10];
  const float* fb1 = (const float*)d_in[11];
  const float* fw2 = (const float*)d_in[12];
  const float* fb2 = (const float*)d_in[13];
  float* out = (float*)d_out;
  char* ws = (char*)d_ws;

  // workspace: qpad @0 (34.08MB, reused as desc after conv3_big); t1pad @34080768
  // (34.08MB, reused as agg); keyn @68161536 (33.55MB); w1b @101715968 (8.39MB);
  // wbuf @110104576 (471KB). peak 110.6MB.
  u16* qpad  = (u16*)(ws);
  u16* t1pad = (u16*)(ws + 34080768);
  u16* keyn  = (u16*)(ws + 68161536);
  u16* w1b   = (u16*)(ws + 101715968);
  u16* wbuf  = (u16*)(ws + 110104576);
  uint4* desc = (uint4*)ws;        // qpad dead after conv3_big
  u16* agg = t1pad;                // t1pad dead after conv_off

  prologue<<<11176, 256, 0, stream>>>(q, key, ow1, ow2, ww1, fw1, fw2,
                                      qpad, keyn, t1pad, wbuf);
  conv3_big<<<1024, 512, 0, stream>>>(qpad, wbuf, ob1, wb1, t1pad, w1b);
  conv_off<<<512, 256, 0, stream>>>(t1pad, wbuf + 184320, ob2, w1b, ww2, wb2, desc);
  sampler<<<32768, 256, 0, stream>>>(desc, keyn, agg);
  conv_fuse<<<dim3(2, 256, 2), 512, 0, stream>>>(agg, wbuf + 202752, wbuf + 219136,
                                                 fb1, fb2, q, out);
}

// Round 9
// 356.644 us; speedup vs baseline: 1.0448x; 1.0010x over previous
//
#include <hip/hip_runtime.h>
#include <hip/hip_fp16.h>

typedef unsigned short u16;
typedef __attribute__((ext_vector_type(8))) short bf16x8;
typedef __attribute__((ext_vector_type(4))) float f32x4;

constexpr int B_ = 2, C_ = 128, H_ = 256, W_ = 256, P_ = H_ * W_;
constexpr int HP_ = 258, WP_ = 258;

union HU { __half2 h; unsigned int u; };

__device__ __forceinline__ float bf2f(u16 u) {
  union { unsigned int i; float f; } v; v.i = ((unsigned int)u) << 16; return v.f;
}
__device__ __forceinline__ u16 f2bf(float f) {
  union { float f; unsigned int i; } v; v.f = f;
  return (u16)((v.i + 0x7fffu + ((v.i >> 16) & 1u)) >> 16);  // RNE
}
// tanh-form GELU via sigmoid; |dev from erf-GELU| <= ~5e-4
__device__ __forceinline__ float gelu_f(float x) {
  float u = x * (1.5957691216057308f + 0.071354816272f * x * x);
  return x / (1.0f + __expf(-u));
}

// async global->LDS, 16B per lane. LDS dest must be wave-uniform base + lane*16.
__device__ __forceinline__ void async16(const u16* g, u16* l) {
  __builtin_amdgcn_global_load_lds(
      (const __attribute__((address_space(1))) unsigned int*)g,
      (__attribute__((address_space(3))) unsigned int*)l, 16, 0, 0);
}

// ---------------- prologue: to_nhwc(q), to_nhwc(key), border-zero x2, repack ----------
// grid: [0,8192) nhwc transposes; [8192,10256) border; [10256,11176) repack
__global__ __launch_bounds__(256) void prologue(
    const float* __restrict__ q, const float* __restrict__ key,
    const float* __restrict__ ow1, const float* __restrict__ ow2,
    const float* __restrict__ ww1, const float* __restrict__ fw1,
    const float* __restrict__ fw2,
    u16* __restrict__ qpad, u16* __restrict__ keyn, u16* __restrict__ t1pad,
    u16* __restrict__ wb) {
  __shared__ u16 l[64 * 66];
  const int id = blockIdx.x, tid = threadIdx.x;
  if (id < 8192) {
    int z = id >> 10, r = id & 1023;
    int bx = r & 3, by = r >> 2;
    const float* in; u16* out; int OW, opad;
    if (z < 4) { in = q; out = qpad; OW = WP_; opad = 1; }
    else { z -= 4; in = key; out = keyn; OW = W_; opad = 0; }
    int b = z >> 1, c0 = (z & 1) * 64;
    int h = by, w0 = bx * 64;
    for (int it = 0; it < 4; ++it) {
      int lin = it * 256 + tid;                 // 1024 float4 quads
      int c = lin >> 4, w4 = (lin & 15) * 4;
      float4 v = *(const float4*)&in[(((size_t)b * C_ + c0 + c) * H_ + h) * W_ + w0 + w4];
      l[c * 66 + w4 + 0] = f2bf(v.x);
      l[c * 66 + w4 + 1] = f2bf(v.y);
      l[c * 66 + w4 + 2] = f2bf(v.z);
      l[c * 66 + w4 + 3] = f2bf(v.w);
    }
    __syncthreads();
    int OH = (opad ? HP_ : H_);
    for (int it = 0; it < 16; ++it) {
      int lin = it * 256 + tid;
      int w = lin >> 6, c = lin & 63;
      out[(((size_t)b * OH + h + opad) * OW + (w0 + w + opad)) * C_ + c0 + c] = l[c * 66 + w];
    }
  } else if (id < 10256) {
    int j = id - 8192;
    u16* buf = (j < 1032) ? qpad : t1pad;
    int idx = ((j < 1032) ? j : j - 1032) * 256 + tid;
    int c = idx & 127;
    int t = idx >> 7;
    int pos = t % 258;
    int side = (t / 258) & 3;
    int b = t / (258 * 4);
    int h, w;
    if (side == 0) { h = 0; w = pos; }
    else if (side == 1) { h = 257; w = pos; }
    else if (side == 2) { h = pos; w = 0; }
    else { h = pos; w = 257; }
    buf[(((size_t)b * HP_ + h) * WP_ + w) * C_ + c] = 0;
  } else {
    // repack weights into wbuf (bf16):
    // W1c @0: ow1+ww1 fragment-packed [tap][cq][g 10][kb 4][lr 16][e 8] = 184320
    // W2 @184320: ow2 packed GT=1, co 8->16 zero-pad = 18432
    // fw1 @202752 row-major [co][ci] 16384 ; fw2 @219136 row-major 16384
    int idx = (id - 10256) * 256 + tid;
    float v;
    if (idx < 184320) {
      int e = idx & 7, lr = (idx >> 3) & 15, kb = (idx >> 7) & 3;
      int t = idx >> 9;
      int g = t % 10, u = t / 10;
      int cq = u & 3, tap = u >> 2;
      int ci = cq * 32 + kb * 8 + e, co = g * 16 + lr;
      v = (co < 128) ? ow1[(co * 128 + ci) * 9 + tap]
                     : ww1[((co - 128) * 128 + ci) * 9 + tap];
    } else if (idx < 202752) {
      int j = idx - 184320;
      int e = j & 7, lr = (j >> 3) & 15, kb = (j >> 7) & 3;
      int cq = (j >> 9) & 3, tap = j >> 11;
      int ci = cq * 32 + kb * 8 + e, co = lr;
      v = (co < 8) ? ow2[(co * 128 + ci) * 9 + tap] : 0.0f;
    } else if (idx < 219136) {
      v = fw1[idx - 202752];
    } else {
      v = fw2[idx - 219136];
    }
    wb[idx] = f2bf(v);
  }
}

// ---------------- combined 3x3 conv (ow1 128->128 + ww1 128->32), band-tiled ----------
// R0-measured structure (74.5 us best): single As buffer, serial stage per ci-quarter,
// weights read directly from global per tap. R2 dbuf (+3 us) and R7 reg-prefetch
// (+13 us, 2x HBM traffic from disrupted write-combining) both REGRESSED — reverted.
__global__ __launch_bounds__(512, 4) void conv3_big(
    const u16* __restrict__ A, const u16* __restrict__ Wf,
    const float* __restrict__ bias1, const float* __restrict__ bias2,
    u16* __restrict__ outb, u16* __restrict__ outw) {
  constexpr int RPX = 36, ROWU = RPX * 32;          // u16 per row-plane = 1152
  __shared__ __align__(16) u16 As[6 * ROWU];        // 13,824 B
  const int tid = threadIdx.x, lane = tid & 63, wave = tid >> 6;  // 8 waves
  const int id = blockIdx.x;
  const int s = id >> 3;
  const int h0 = (((id & 7) << 3) | (s & 7)) << 2;  // 4-row band
  const int w0 = ((s >> 3) & 7) << 5;
  const int b = s >> 6;
  const int wr = wave >> 1, wc = wave & 1;          // wr: row 0..3, wc: co half
  const int wn = wc * 80;
  const int lr = lane & 15, kq = lane >> 4;
  const int gbase = wn >> 4;                        // 0 or 5

  int preA[2][3];
#pragma unroll
  for (int i = 0; i < 2; i++)
#pragma unroll
    for (int kx = 0; kx < 3; kx++) {
      int pxv = i * 16 + lr + kx;
      preA[i][kx] = (pxv * 4 + (kq ^ ((pxv >> 1) & 3))) * 8;  // u16 units
    }

  f32x4 acc[2][5];
#pragma unroll
  for (int i = 0; i < 2; i++)
#pragma unroll
    for (int j = 0; j < 5; j++) { f32x4 z = {0.f, 0.f, 0.f, 0.f}; acc[i][j] = z; }

  for (int cq = 0; cq < 4; ++cq) {
    const int ci0 = cq * 32;
    __syncthreads();
    for (int i = tid; i < 864; i += 512) {
      int ry = i / 144;
      int rem = i - ry * 144;
      int px = rem >> 2, c8 = rem & 3;
      int g = c8 ^ ((px >> 1) & 3);
      async16(A + ((size_t)(b * HP_ + h0 + ry) * WP_ + (w0 + px)) * 128 + ci0 + g * 8,
              As + i * 8);
    }
    __syncthreads();
#pragma unroll
    for (int tap = 0; tap < 9; ++tap) {
      const int ky = tap / 3, kx = tap % 3;
      bf16x8 bfr[5], af[2];
#pragma unroll
      for (int j = 0; j < 5; ++j)
        bfr[j] = *(const bf16x8*)&Wf[(size_t)((((tap * 4 + cq) * 10 + gbase + j) * 4 + kq) * 16 + lr) * 8];
#pragma unroll
      for (int i = 0; i < 2; ++i)
        af[i] = *(const bf16x8*)&As[(wr + ky) * ROWU + preA[i][kx]];
#pragma unroll
      for (int i = 0; i < 2; i++)
#pragma unroll
        for (int j = 0; j < 5; j++)
          acc[i][j] = __builtin_amdgcn_mfma_f32_16x16x32_bf16(af[i], bfr[j], acc[i][j], 0, 0, 0);
    }
  }

  const int h = h0 + wr;
#pragma unroll
  for (int i = 0; i < 2; i++) {
#pragma unroll
    for (int j = 0; j < 5; j++) {
      const int co = wn + j * 16 + lr;
#pragma unroll
      for (int r = 0; r < 4; r++) {
        const int w = w0 + i * 16 + kq * 4 + r;
        float v = acc[i][j][r];
        if (co < 128) {
          v = gelu_f(v + bias1[co]);
          outb[(((size_t)b * HP_ + h + 1) * WP_ + (w + 1)) * 128 + co] = f2bf(v);
        } else {
          v = gelu_f(v + bias2[co - 128]);
          outw[((size_t)b * P_ + (size_t)h * W_ + w) * 32 + (co - 128)] = f2bf(v);
        }
      }
    }
  }
}

// ---------------- offsets conv (3x3 128->8) + fused prep epilogue ---------------------
// BM=256 as 4 rows x 64 px; BN=16; wave = one row. Epilogue: offs->LDS regroup,
// then per-thread pixel: logits(32->4), softmax, grid math -> desc.
__global__ __launch_bounds__(256) void conv_off(
    const u16* __restrict__ A, const u16* __restrict__ Wf,
    const float* __restrict__ bias,
    const u16* __restrict__ w1b, const float* __restrict__ ww2,
    const float* __restrict__ wb2, uint4* __restrict__ desc) {
  constexpr int RPX = 66, ROWU = RPX * 32;          // 2112 u16 per row-plane
  __shared__ __align__(16) u16 As[6 * ROWU];        // 25,344 B
  float* off_lds = (float*)As;                      // reused after K-loop (256*9*4 B)
  const int tid = threadIdx.x, lane = tid & 63, wave = tid >> 6;
  const int id = blockIdx.x;
  const int s = id >> 3;
  const int h0 = (((id & 7) << 3) | (s & 7)) << 2;
  const int w0 = ((s >> 3) & 3) << 6;
  const int b = s >> 5;
  const int lr = lane & 15, kq = lane >> 4;

  int preA[4][3];
#pragma unroll
  for (int i = 0; i < 4; i++)
#pragma unroll
    for (int kx = 0; kx < 3; kx++) {
      int pxv = i * 16 + lr + kx;
      preA[i][kx] = (pxv * 4 + (kq ^ ((pxv >> 1) & 3))) * 8;
    }

  f32x4 acc[4];
#pragma unroll
  for (int i = 0; i < 4; i++) { f32x4 z = {0.f, 0.f, 0.f, 0.f}; acc[i] = z; }

  for (int cq = 0; cq < 4; ++cq) {
    const int ci0 = cq * 32;
    __syncthreads();
    for (int i = tid; i < 1584; i += 256) {
      int ry = i / 264;
      int rem = i - ry * 264;
      int px = rem >> 2, c8 = rem & 3;
      int g = c8 ^ ((px >> 1) & 3);
      async16(A + ((size_t)(b * HP_ + h0 + ry) * WP_ + (w0 + px)) * 128 + ci0 + g * 8,
              As + i * 8);
    }
    __syncthreads();
#pragma unroll
    for (int tap = 0; tap < 9; ++tap) {
      const int ky = tap / 3, kx = tap % 3;
      bf16x8 bw = *(const bf16x8*)&Wf[(size_t)(((tap * 4 + cq) * 4 + kq) * 16 + lr) * 8];
      bf16x8 af[4];
#pragma unroll
      for (int i = 0; i < 4; ++i)
        af[i] = *(const bf16x8*)&As[(wave + ky) * ROWU + preA[i][kx]];
#pragma unroll
      for (int i = 0; i < 4; i++)
        acc[i] = __builtin_amdgcn_mfma_f32_16x16x32_bf16(af[i], bw, acc[i], 0, 0, 0);
    }
  }

  __syncthreads();  // staging region dead; reuse as off_lds
#pragma unroll
  for (int i = 0; i < 4; i++) {
#pragma unroll
    for (int r = 0; r < 4; r++) {
      if (lr < 8) {
        int px = i * 16 + (lane >> 4) * 4 + r;
        off_lds[(wave * 64 + px) * 9 + lr] = acc[i][r] + bias[lr];
      }
    }
  }
  __syncthreads();

  // one pixel per thread
  const int pp = tid;
  const int h = h0 + (pp >> 6), w = w0 + (pp & 63);
  const int pix = b * P_ + h * W_ + w;
  const u16* wp = w1b + (size_t)pix * 32;
  float f[32];
#pragma unroll
  for (int i = 0; i < 32; i += 2) {
    unsigned u = *(const unsigned*)&wp[i];
    f[i] = bf2f((u16)u); f[i + 1] = bf2f((u16)(u >> 16));
  }
  float lg[4];
#pragma unroll
  for (int k = 0; k < 4; k++) {
    float sacc = wb2[k];
#pragma unroll
    for (int i = 0; i < 32; i++) sacc = fmaf(ww2[k * 32 + i], f[i], sacc);
    lg[k] = sacc;
  }
  float mx = fmaxf(fmaxf(lg[0], lg[1]), fmaxf(lg[2], lg[3]));
  float e[4], sum = 0.f;
#pragma unroll
  for (int k = 0; k < 4; k++) { e[k] = __expf(lg[k] - mx); sum += e[k]; }
  const float inv = 1.0f / sum;
#pragma unroll
  for (int k = 0; k < 4; k++) {
    float ox = off_lds[pp * 9 + 2 * k], oy = off_lds[pp * 9 + 2 * k + 1];
    float gx = (2.0f * w / 255.0f - 1.0f) + ox * (1.0f / 128.0f);
    float gy = (2.0f * h / 255.0f - 1.0f) + oy * (1.0f / 128.0f);
    gx = fminf(fmaxf(gx, -1.f), 1.f);
    gy = fminf(fmaxf(gy, -1.f), 1.f);
    float px = fminf(fmaxf((gx + 1.f) * 127.5f, 0.f), 255.f);
    float py = fminf(fmaxf((gy + 1.f) * 127.5f, 0.f), 255.f);
    int x0 = (int)px, y0 = (int)py;
    int x1 = min(x0 + 1, 255), y1 = min(y0 + 1, 255);
    float wx = px - x0, wy = py - y0;
    float wk = e[k] * inv;
    float w00 = (1.f - wx) * (1.f - wy) * wk, w01 = wx * (1.f - wy) * wk;
    float w10 = (1.f - wx) * wy * wk,         w11 = wx * wy * wk;
    HU t01, t23;
    t01.h = __floats2half2_rn(w00, w01);
    t23.h = __floats2half2_rn(w10, w11);
    uint4 d;
    d.x = (unsigned)(y0 * 256 + x0) | ((unsigned)(x1 - x0) << 16) | ((unsigned)(y1 - y0) << 17);
    d.y = t01.u; d.z = t23.u; d.w = 0;
    desc[(size_t)pix * 4 + k] = d;
  }
}

// ---------------- fused sample + 1x1 conv + GELU + 1x1 conv + residual ---------------
// NEW: sampler folded in as phase 0 — each wave gathers 16 px (4 samples x 4 corners,
// 256B coalesced reads from L3-resident keyn) and writes the bilinear result DIRECTLY
// into the GEMM1 A-tile in LDS (same XOR-chunk swizzle the async16 staging produced).
// Kills the 67 MB agg HBM round-trip + one kernel launch. Bs for GEMM1 borrows the T2
// region (dead until after GEMM1). LDS: SM 32KB (As -> later W2) + T2 34.8KB = 66.8KB
// -> 2 blocks/CU (unchanged vs separate conv_fuse).
__global__ __launch_bounds__(512, 4) void sample_fuse(
    const uint4* __restrict__ desc, const u16* __restrict__ keyn,
    const u16* __restrict__ W1, const u16* __restrict__ W2,
    const float* __restrict__ b1, const float* __restrict__ b2,
    const float* __restrict__ resid, float* __restrict__ out) {
  __shared__ __align__(16) u16 SM[128 * 128];  // phase0/1: As full (px 128 x ci 128); phase2: W2
  __shared__ __align__(16) u16 T2[128 * 136];  // GEMM1: Bs half (8192 u16); then GELU tile
  const int tid = threadIdx.x, lane = tid & 63, wave = tid >> 6;  // 8 waves
  const int h = blockIdx.y, w0 = blockIdx.x * 128;
  const int b = blockIdx.z;
  const int wr = wave >> 1, wc = wave & 1;
  const int wm = wr * 32, wn = wc * 64;
  const int lr = lane & 15, kq = lane >> 4;
  const int sw = lr & 7;

  // ---- phase 0: deformable sampling for this block's 128 px -> As (SM), swizzled
  {
    const u16* kb = keyn + (size_t)b * (P_ * C_) + 2 * lane;
    const int pxbase = wave * 16;
    const size_t pixbase = (size_t)b * P_ + (size_t)h * W_ + w0 + pxbase;
    const int half64 = (lane >> 5) * 64;      // ci half (0/1) this lane's pair lives in
    const int gg = (lane >> 2) & 7;           // source 8-ch chunk within half
    const int e2 = (lane & 3) * 2;            // u16 offset within chunk
    for (int p = 0; p < 16; ++p) {
      const size_t pix = pixbase + p;
      float a0 = 0.f, a1 = 0.f;
#pragma unroll
      for (int k = 0; k < 4; ++k) {
        uint4 d = desc[pix * 4 + k];
        const int boff = (int)(d.x & 0xFFFFu) << 7;
        const int o01 = (int)((d.x >> 16) & 1u) << 7;
        const int o10 = (int)((d.x >> 17) & 1u) << 15;
        const u16* c0 = kb + boff;
        unsigned u00 = *(const unsigned*)(c0);
        unsigned u01 = *(const unsigned*)(c0 + o01);
        unsigned u10 = *(const unsigned*)(c0 + o10);
        unsigned u11 = *(const unsigned*)(c0 + o10 + o01);
        HU t01, t23; t01.u = d.y; t23.u = d.z;
        float2 wA = __half22float2(t01.h);
        float2 wB = __half22float2(t23.h);
        a0 = fmaf(wA.x, bf2f((u16)u00), a0);
        a0 = fmaf(wA.y, bf2f((u16)u01), a0);
        a0 = fmaf(wB.x, bf2f((u16)u10), a0);
        a0 = fmaf(wB.y, bf2f((u16)u11), a0);
        a1 = fmaf(wA.x, bf2f((u16)(u00 >> 16)), a1);
        a1 = fmaf(wA.y, bf2f((u16)(u01 >> 16)), a1);
        a1 = fmaf(wB.x, bf2f((u16)(u10 >> 16)), a1);
        a1 = fmaf(wB.y, bf2f((u16)(u11 >> 16)), a1);
      }
      const int px = pxbase + p;
      unsigned outu = ((unsigned)f2bf(a1) << 16) | (unsigned)f2bf(a0);
      // As[px][half*64 + (gg^(px&7))*8 + e2] — source chunk gg at swizzled position
      *(unsigned*)&SM[px * 128 + half64 + ((gg ^ (px & 7)) << 3) + e2] = outu;
    }
  }

  f32x4 acc[2][4];
#pragma unroll
  for (int i = 0; i < 2; i++)
#pragma unroll
    for (int j = 0; j < 4; j++) { f32x4 z = {0.f, 0.f, 0.f, 0.f}; acc[i][j] = z; }

  // ---- GEMM1: As(SM, 128px x 128ci) @ fw1 -> acc ; Bs staged per ci-half into T2
  for (int c = 0; c < 2; ++c) {
    const int ci0 = c << 6;
    const u16* Wb = W1 + ci0;
    __syncthreads();   // c=0: As ds_writes visible; c=1: protect T2 from c=0 readers
    for (int i = tid; i < 1024; i += 512) {
      int r = i >> 3, cb = i & 7;
      async16(Wb + r * 128 + ((cb ^ (r & 7)) << 3), T2 + i * 8);
    }
    __syncthreads();
#pragma unroll
    for (int ks = 0; ks < 2; ++ks) {
      const int kb = ks * 4 + kq;
      bf16x8 af[2], bfr[4];
#pragma unroll
      for (int i = 0; i < 2; i++)
        af[i] = *(const bf16x8*)&SM[(wm + i * 16 + lr) * 128 + ci0 + ((kb ^ sw) << 3)];
#pragma unroll
      for (int j = 0; j < 4; j++)
        bfr[j] = *(const bf16x8*)&T2[(wn + j * 16 + lr) * 64 + ((kb ^ sw) << 3)];
#pragma unroll
      for (int i = 0; i < 2; i++)
#pragma unroll
        for (int j = 0; j < 4; j++)
          acc[i][j] = __builtin_amdgcn_mfma_f32_16x16x32_bf16(af[i], bfr[j], acc[i][j], 0, 0, 0);
    }
  }
  __syncthreads();   // GEMM1 done: SM (As) and T2 (Bs) both dead

  // ---- stage fw2 into SM (async, overlaps GELU VALU work), GELU -> T2 (pitch 136)
  for (int i = tid; i < 2048; i += 512) {   // 128co x 16 chunks
    int r = i >> 4, sl = i & 15;
    int g = sl ^ (r & 7);
    async16(W2 + r * 128 + g * 8, SM + i * 8);
  }
#pragma unroll
  for (int i = 0; i < 2; i++)
#pragma unroll
    for (int j = 0; j < 4; j++) {
      const int co = wn + j * 16 + lr;
#pragma unroll
      for (int r = 0; r < 4; r++) {
        const int px = wm + i * 16 + kq * 4 + r;
        T2[px * 136 + co] = f2bf(gelu_f(acc[i][j][r] + b1[co]));
      }
    }
  __syncthreads();   // drains async W2 loads + T2 ds_writes

  // ---- GEMM2: T2(128px x 128k) @ fw2 -> acc
#pragma unroll
  for (int i = 0; i < 2; i++)
#pragma unroll
    for (int j = 0; j < 4; j++) { f32x4 z = {0.f, 0.f, 0.f, 0.f}; acc[i][j] = z; }
#pragma unroll
  for (int ks = 0; ks < 4; ++ks) {
    const int kc = ks * 4 + kq;
    bf16x8 af[2], bfr[4];
#pragma unroll
    for (int i = 0; i < 2; i++)
      af[i] = *(const bf16x8*)&T2[(wm + i * 16 + lr) * 136 + kc * 8];
#pragma unroll
    for (int j = 0; j < 4; j++) {
      int rr = wn + j * 16 + lr;
      bfr[j] = *(const bf16x8*)&SM[rr * 128 + (kc ^ (rr & 7)) * 8];
    }
#pragma unroll
    for (int i = 0; i < 2; i++)
#pragma unroll
      for (int j = 0; j < 4; j++)
        acc[i][j] = __builtin_amdgcn_mfma_f32_16x16x32_bf16(af[i], bfr[j], acc[i][j], 0, 0, 0);
  }

  // ---- residual epilogue (fp32 NCHW)
#pragma unroll
  for (int i = 0; i < 2; i++) {
#pragma unroll
    for (int j = 0; j < 4; j++) {
      const int co = wn + j * 16 + lr;
      const int w = w0 + wm + i * 16 + kq * 4;
      size_t idx = ((size_t)b * 128 + co) * (size_t)P_ + (size_t)h * W_ + w;
      float4 rv = *(const float4*)&resid[idx];
      float bi = b2[co];
      float4 ov;
      ov.x = rv.x + 0.3f * (acc[i][j][0] + bi);
      ov.y = rv.y + 0.3f * (acc[i][j][1] + bi);
      ov.z = rv.z + 0.3f * (acc[i][j][2] + bi);
      ov.w = rv.w + 0.3f * (acc[i][j][3] + bi);
      *(float4*)&out[idx] = ov;
    }
  }
}

extern "C" void kernel_launch(void* const* d_in, const int* in_sizes, int n_in,
                              void* d_out, int out_size, void* d_ws, size_t ws_size,
                              hipStream_t stream) {
  (void)in_sizes; (void)n_in; (void)out_size; (void)ws_size;
  const float* q   = (const float*)d_in[0];
  const float* key = (const float*)d_in[1];
  const float* ow1 = (const float*)d_in[2];
  const float* ob1 = (const float*)d_in[3];
  const float* ow2 = (const float*)d_in[4];
  const float* ob2 = (const float*)d_in[5];
  const float* ww1 = (const float*)d_in[6];
  const float* wb1 = (const float*)d_in[7];
  const float* ww2 = (const float*)d_in[8];
  const float* wb2 = (const float*)d_in[9];
  const float* fw1 = (const float*)d_in[10];
  const float* fb1 = (const float*)d_in[11];
  const float* fw2 = (const float*)d_in[12];
  const float* fb2 = (const float*)d_in[13];
  float* out = (float*)d_out;
  char* ws = (char*)d_ws;

  // workspace: qpad @0 (34.08MB, reused as desc after conv3_big); t1pad @34080768
  // (34.08MB); keyn @68161536 (33.55MB); w1b @101715968 (8.39MB);
  // wbuf @110104576 (471KB). peak 110.6MB. (agg buffer eliminated by sample_fuse.)
  u16* qpad  = (u16*)(ws);
  u16* t1pad = (u16*)(ws + 34080768);
  u16* keyn  = (u16*)(ws + 68161536);
  u16* w1b   = (u16*)(ws + 101715968);
  u16* wbuf  = (u16*)(ws + 110104576);
  uint4* desc = (uint4*)ws;        // qpad dead after conv3_big

  prologue<<<11176, 256, 0, stream>>>(q, key, ow1, ow2, ww1, fw1, fw2,
                                      qpad, keyn, t1pad, wbuf);
  conv3_big<<<1024, 512, 0, stream>>>(qpad, wbuf, ob1, wb1, t1pad, w1b);
  conv_off<<<512, 256, 0, stream>>>(t1pad, wbuf + 184320, ob2, w1b, ww2, wb2, desc);
  sample_fuse<<<dim3(2, 256, 2), 512, 0, stream>>>(desc, keyn, wbuf + 202752,
                                                   wbuf + 219136, fb1, fb2, q, out);
}

// Round 10
// 351.874 us; speedup vs baseline: 1.0589x; 1.0136x over previous
//
#include <hip/hip_runtime.h>
#include <hip/hip_fp16.h>

typedef unsigned short u16;
typedef __attribute__((ext_vector_type(8))) short bf16x8;
typedef __attribute__((ext_vector_type(4))) float f32x4;

constexpr int B_ = 2, C_ = 128, H_ = 256, W_ = 256, P_ = H_ * W_;
constexpr int HP_ = 258, WP_ = 258;

union HU { __half2 h; unsigned int u; };

__device__ __forceinline__ float bf2f(u16 u) {
  union { unsigned int i; float f; } v; v.i = ((unsigned int)u) << 16; return v.f;
}
__device__ __forceinline__ u16 f2bf(float f) {
  union { float f; unsigned int i; } v; v.f = f;
  return (u16)((v.i + 0x7fffu + ((v.i >> 16) & 1u)) >> 16);  // RNE
}
// tanh-form GELU via sigmoid; |dev from erf-GELU| <= ~5e-4
__device__ __forceinline__ float gelu_f(float x) {
  float u = x * (1.5957691216057308f + 0.071354816272f * x * x);
  return x / (1.0f + __expf(-u));
}

// async global->LDS, 16B per lane. LDS dest must be wave-uniform base + lane*16.
__device__ __forceinline__ void async16(const u16* g, u16* l) {
  __builtin_amdgcn_global_load_lds(
      (const __attribute__((address_space(1))) unsigned int*)g,
      (__attribute__((address_space(3))) unsigned int*)l, 16, 0, 0);
}

// ---------------- prologue: to_nhwc(q), to_nhwc(key), border-zero x2, repack ----------
// grid: [0,8192) nhwc transposes; [8192,10256) border; [10256,11176) repack
__global__ __launch_bounds__(256) void prologue(
    const float* __restrict__ q, const float* __restrict__ key,
    const float* __restrict__ ow1, const float* __restrict__ ow2,
    const float* __restrict__ ww1, const float* __restrict__ fw1,
    const float* __restrict__ fw2,
    u16* __restrict__ qpad, u16* __restrict__ keyn, u16* __restrict__ t1pad,
    u16* __restrict__ wb) {
  __shared__ u16 l[64 * 66];
  const int id = blockIdx.x, tid = threadIdx.x;
  if (id < 8192) {
    int z = id >> 10, r = id & 1023;
    int bx = r & 3, by = r >> 2;
    const float* in; u16* out; int OW, opad;
    if (z < 4) { in = q; out = qpad; OW = WP_; opad = 1; }
    else { z -= 4; in = key; out = keyn; OW = W_; opad = 0; }
    int b = z >> 1, c0 = (z & 1) * 64;
    int h = by, w0 = bx * 64;
    for (int it = 0; it < 4; ++it) {
      int lin = it * 256 + tid;                 // 1024 float4 quads
      int c = lin >> 4, w4 = (lin & 15) * 4;
      float4 v = *(const float4*)&in[(((size_t)b * C_ + c0 + c) * H_ + h) * W_ + w0 + w4];
      l[c * 66 + w4 + 0] = f2bf(v.x);
      l[c * 66 + w4 + 1] = f2bf(v.y);
      l[c * 66 + w4 + 2] = f2bf(v.z);
      l[c * 66 + w4 + 3] = f2bf(v.w);
    }
    __syncthreads();
    int OH = (opad ? HP_ : H_);
    for (int it = 0; it < 16; ++it) {
      int lin = it * 256 + tid;
      int w = lin >> 6, c = lin & 63;
      out[(((size_t)b * OH + h + opad) * OW + (w0 + w + opad)) * C_ + c0 + c] = l[c * 66 + w];
    }
  } else if (id < 10256) {
    int j = id - 8192;
    u16* buf = (j < 1032) ? qpad : t1pad;
    int idx = ((j < 1032) ? j : j - 1032) * 256 + tid;
    int c = idx & 127;
    int t = idx >> 7;
    int pos = t % 258;
    int side = (t / 258) & 3;
    int b = t / (258 * 4);
    int h, w;
    if (side == 0) { h = 0; w = pos; }
    else if (side == 1) { h = 257; w = pos; }
    else if (side == 2) { h = pos; w = 0; }
    else { h = pos; w = 257; }
    buf[(((size_t)b * HP_ + h) * WP_ + w) * C_ + c] = 0;
  } else {
    // repack weights into wbuf (bf16):
    // W1c @0: ow1+ww1 fragment-packed [tap][cq][g 10][kb 4][lr 16][e 8] = 184320
    // W2 @184320: ow2 packed GT=1, co 8->16 zero-pad = 18432
    // fw1 @202752 row-major [co][ci] 16384 ; fw2 @219136 row-major 16384
    int idx = (id - 10256) * 256 + tid;
    float v;
    if (idx < 184320) {
      int e = idx & 7, lr = (idx >> 3) & 15, kb = (idx >> 7) & 3;
      int t = idx >> 9;
      int g = t % 10, u = t / 10;
      int cq = u & 3, tap = u >> 2;
      int ci = cq * 32 + kb * 8 + e, co = g * 16 + lr;
      v = (co < 128) ? ow1[(co * 128 + ci) * 9 + tap]
                     : ww1[((co - 128) * 128 + ci) * 9 + tap];
    } else if (idx < 202752) {
      int j = idx - 184320;
      int e = j & 7, lr = (j >> 3) & 15, kb = (j >> 7) & 3;
      int cq = (j >> 9) & 3, tap = j >> 11;
      int ci = cq * 32 + kb * 8 + e, co = lr;
      v = (co < 8) ? ow2[(co * 128 + ci) * 9 + tap] : 0.0f;
    } else if (idx < 219136) {
      v = fw1[idx - 202752];
    } else {
      v = fw2[idx - 219136];
    }
    wb[idx] = f2bf(v);
  }
}

// ---------------- combined 3x3 conv (ow1 128->128 + ww1 128->32), band-tiled ----------
// R0-measured structure (74.5 us best): single As buffer, serial stage per ci-quarter,
// weights read directly from global per tap. R2 dbuf (+3 us) and R7 reg-prefetch
// (+13 us, 2x HBM traffic from disrupted write-combining) both REGRESSED — reverted.
__global__ __launch_bounds__(512, 4) void conv3_big(
    const u16* __restrict__ A, const u16* __restrict__ Wf,
    const float* __restrict__ bias1, const float* __restrict__ bias2,
    u16* __restrict__ outb, u16* __restrict__ outw) {
  constexpr int RPX = 36, ROWU = RPX * 32;          // u16 per row-plane = 1152
  __shared__ __align__(16) u16 As[6 * ROWU];        // 13,824 B
  const int tid = threadIdx.x, lane = tid & 63, wave = tid >> 6;  // 8 waves
  const int id = blockIdx.x;
  const int s = id >> 3;
  const int h0 = (((id & 7) << 3) | (s & 7)) << 2;  // 4-row band
  const int w0 = ((s >> 3) & 7) << 5;
  const int b = s >> 6;
  const int wr = wave >> 1, wc = wave & 1;          // wr: row 0..3, wc: co half
  const int wn = wc * 80;
  const int lr = lane & 15, kq = lane >> 4;
  const int gbase = wn >> 4;                        // 0 or 5

  int preA[2][3];
#pragma unroll
  for (int i = 0; i < 2; i++)
#pragma unroll
    for (int kx = 0; kx < 3; kx++) {
      int pxv = i * 16 + lr + kx;
      preA[i][kx] = (pxv * 4 + (kq ^ ((pxv >> 1) & 3))) * 8;  // u16 units
    }

  f32x4 acc[2][5];
#pragma unroll
  for (int i = 0; i < 2; i++)
#pragma unroll
    for (int j = 0; j < 5; j++) { f32x4 z = {0.f, 0.f, 0.f, 0.f}; acc[i][j] = z; }

  for (int cq = 0; cq < 4; ++cq) {
    const int ci0 = cq * 32;
    __syncthreads();
    for (int i = tid; i < 864; i += 512) {
      int ry = i / 144;
      int rem = i - ry * 144;
      int px = rem >> 2, c8 = rem & 3;
      int g = c8 ^ ((px >> 1) & 3);
      async16(A + ((size_t)(b * HP_ + h0 + ry) * WP_ + (w0 + px)) * 128 + ci0 + g * 8,
              As + i * 8);
    }
    __syncthreads();
#pragma unroll
    for (int tap = 0; tap < 9; ++tap) {
      const int ky = tap / 3, kx = tap % 3;
      bf16x8 bfr[5], af[2];
#pragma unroll
      for (int j = 0; j < 5; ++j)
        bfr[j] = *(const bf16x8*)&Wf[(size_t)((((tap * 4 + cq) * 10 + gbase + j) * 4 + kq) * 16 + lr) * 8];
#pragma unroll
      for (int i = 0; i < 2; ++i)
        af[i] = *(const bf16x8*)&As[(wr + ky) * ROWU + preA[i][kx]];
#pragma unroll
      for (int i = 0; i < 2; i++)
#pragma unroll
        for (int j = 0; j < 5; j++)
          acc[i][j] = __builtin_amdgcn_mfma_f32_16x16x32_bf16(af[i], bfr[j], acc[i][j], 0, 0, 0);
    }
  }

  const int h = h0 + wr;
#pragma unroll
  for (int i = 0; i < 2; i++) {
#pragma unroll
    for (int j = 0; j < 5; j++) {
      const int co = wn + j * 16 + lr;
#pragma unroll
      for (int r = 0; r < 4; r++) {
        const int w = w0 + i * 16 + kq * 4 + r;
        float v = acc[i][j][r];
        if (co < 128) {
          v = gelu_f(v + bias1[co]);
          outb[(((size_t)b * HP_ + h + 1) * WP_ + (w + 1)) * 128 + co] = f2bf(v);
        } else {
          v = gelu_f(v + bias2[co - 128]);
          outw[((size_t)b * P_ + (size_t)h * W_ + w) * 32 + (co - 128)] = f2bf(v);
        }
      }
    }
  }
}

// ---------------- offsets conv (3x3 128->8) + fused prep epilogue ---------------------
// BM=256 as 4 rows x 64 px; BN=16; wave = one row. NEW: 2 ci-quarters staged per round
// into As[2] (50.7KB LDS) — ~12 async16/thread issued before ONE drain, 2 rounds
// instead of 4. Halves the serial barrier-latency chain (kernel was latency-bound at
// 8 waves/CU with tiny compute). Epilogue unchanged.
__global__ __launch_bounds__(256) void conv_off(
    const u16* __restrict__ A, const u16* __restrict__ Wf,
    const float* __restrict__ bias,
    const u16* __restrict__ w1b, const float* __restrict__ ww2,
    const float* __restrict__ wb2, uint4* __restrict__ desc) {
  constexpr int RPX = 66, ROWU = RPX * 32;          // 2112 u16 per row-plane
  __shared__ __align__(16) u16 As[2][6 * ROWU];     // 2 x 25,344 B = 50,688 B
  float* off_lds = (float*)As;                      // reused after K-loop (256*9*4 B)
  const int tid = threadIdx.x, lane = tid & 63, wave = tid >> 6;
  const int id = blockIdx.x;
  const int s = id >> 3;
  const int h0 = (((id & 7) << 3) | (s & 7)) << 2;
  const int w0 = ((s >> 3) & 3) << 6;
  const int b = s >> 5;
  const int lr = lane & 15, kq = lane >> 4;

  int preA[4][3];
#pragma unroll
  for (int i = 0; i < 4; i++)
#pragma unroll
    for (int kx = 0; kx < 3; kx++) {
      int pxv = i * 16 + lr + kx;
      preA[i][kx] = (pxv * 4 + (kq ^ ((pxv >> 1) & 3))) * 8;
    }

  f32x4 acc[4];
#pragma unroll
  for (int i = 0; i < 4; i++) { f32x4 z = {0.f, 0.f, 0.f, 0.f}; acc[i] = z; }

  for (int r = 0; r < 2; ++r) {
    __syncthreads();                                // protect As from prev round readers
    // stage BOTH quarters of this round back-to-back: one deep pipeline, one drain
#pragma unroll
    for (int half = 0; half < 2; ++half) {
      const int ci0 = (r * 2 + half) * 32;
      for (int i = tid; i < 1584; i += 256) {
        int ry = i / 264;
        int rem = i - ry * 264;
        int px = rem >> 2, c8 = rem & 3;
        int g = c8 ^ ((px >> 1) & 3);
        async16(A + ((size_t)(b * HP_ + h0 + ry) * WP_ + (w0 + px)) * 128 + ci0 + g * 8,
                As[half] + i * 8);
      }
    }
    __syncthreads();                                // single drain per round
#pragma unroll
    for (int half = 0; half < 2; ++half) {
      const int cq = r * 2 + half;
      const u16* Ac = As[half];
#pragma unroll
      for (int tap = 0; tap < 9; ++tap) {
        const int ky = tap / 3, kx = tap % 3;
        bf16x8 bw = *(const bf16x8*)&Wf[(size_t)(((tap * 4 + cq) * 4 + kq) * 16 + lr) * 8];
        bf16x8 af[4];
#pragma unroll
        for (int i = 0; i < 4; ++i)
          af[i] = *(const bf16x8*)&Ac[(wave + ky) * ROWU + preA[i][kx]];
#pragma unroll
        for (int i = 0; i < 4; i++)
          acc[i] = __builtin_amdgcn_mfma_f32_16x16x32_bf16(af[i], bw, acc[i], 0, 0, 0);
      }
    }
  }

  __syncthreads();  // staging region dead; reuse as off_lds
#pragma unroll
  for (int i = 0; i < 4; i++) {
#pragma unroll
    for (int r = 0; r < 4; r++) {
      if (lr < 8) {
        int px = i * 16 + (lane >> 4) * 4 + r;
        off_lds[(wave * 64 + px) * 9 + lr] = acc[i][r] + bias[lr];
      }
    }
  }
  __syncthreads();

  // one pixel per thread
  const int pp = tid;
  const int h = h0 + (pp >> 6), w = w0 + (pp & 63);
  const int pix = b * P_ + h * W_ + w;
  const u16* wp = w1b + (size_t)pix * 32;
  float f[32];
#pragma unroll
  for (int i = 0; i < 32; i += 2) {
    unsigned u = *(const unsigned*)&wp[i];
    f[i] = bf2f((u16)u); f[i + 1] = bf2f((u16)(u >> 16));
  }
  float lg[4];
#pragma unroll
  for (int k = 0; k < 4; k++) {
    float sacc = wb2[k];
#pragma unroll
    for (int i = 0; i < 32; i++) sacc = fmaf(ww2[k * 32 + i], f[i], sacc);
    lg[k] = sacc;
  }
  float mx = fmaxf(fmaxf(lg[0], lg[1]), fmaxf(lg[2], lg[3]));
  float e[4], sum = 0.f;
#pragma unroll
  for (int k = 0; k < 4; k++) { e[k] = __expf(lg[k] - mx); sum += e[k]; }
  const float inv = 1.0f / sum;
#pragma unroll
  for (int k = 0; k < 4; k++) {
    float ox = off_lds[pp * 9 + 2 * k], oy = off_lds[pp * 9 + 2 * k + 1];
    float gx = (2.0f * w / 255.0f - 1.0f) + ox * (1.0f / 128.0f);
    float gy = (2.0f * h / 255.0f - 1.0f) + oy * (1.0f / 128.0f);
    gx = fminf(fmaxf(gx, -1.f), 1.f);
    gy = fminf(fmaxf(gy, -1.f), 1.f);
    float px = fminf(fmaxf((gx + 1.f) * 127.5f, 0.f), 255.f);
    float py = fminf(fmaxf((gy + 1.f) * 127.5f, 0.f), 255.f);
    int x0 = (int)px, y0 = (int)py;
    int x1 = min(x0 + 1, 255), y1 = min(y0 + 1, 255);
    float wx = px - x0, wy = py - y0;
    float wk = e[k] * inv;
    float w00 = (1.f - wx) * (1.f - wy) * wk, w01 = wx * (1.f - wy) * wk;
    float w10 = (1.f - wx) * wy * wk,         w11 = wx * wy * wk;
    HU t01, t23;
    t01.h = __floats2half2_rn(w00, w01);
    t23.h = __floats2half2_rn(w10, w11);
    uint4 d;
    d.x = (unsigned)(y0 * 256 + x0) | ((unsigned)(x1 - x0) << 16) | ((unsigned)(y1 - y0) << 17);
    d.y = t01.u; d.z = t23.u; d.w = 0;
    desc[(size_t)pix * 4 + k] = d;
  }
}

// ---------------- fused sample + 1x1 conv + GELU + 1x1 conv + residual ---------------
// sampler folded in as phase 0 — each wave gathers 16 px (4 samples x 4 corners,
// 256B coalesced reads from L3-resident keyn) and writes the bilinear result DIRECTLY
// into the GEMM1 A-tile in LDS (same XOR-chunk swizzle the async16 staging produced).
// Kills the 67 MB agg HBM round-trip + one kernel launch. Bs for GEMM1 borrows the T2
// region (dead until after GEMM1). LDS: SM 32KB (As -> later W2) + T2 34.8KB = 66.8KB
// -> 2 blocks/CU (unchanged vs separate conv_fuse).
__global__ __launch_bounds__(512, 4) void sample_fuse(
    const uint4* __restrict__ desc, const u16* __restrict__ keyn,
    const u16* __restrict__ W1, const u16* __restrict__ W2,
    const float* __restrict__ b1, const float* __restrict__ b2,
    const float* __restrict__ resid, float* __restrict__ out) {
  __shared__ __align__(16) u16 SM[128 * 128];  // phase0/1: As full (px 128 x ci 128); phase2: W2
  __shared__ __align__(16) u16 T2[128 * 136];  // GEMM1: Bs half (8192 u16); then GELU tile
  const int tid = threadIdx.x, lane = tid & 63, wave = tid >> 6;  // 8 waves
  const int h = blockIdx.y, w0 = blockIdx.x * 128;
  const int b = blockIdx.z;
  const int wr = wave >> 1, wc = wave & 1;
  const int wm = wr * 32, wn = wc * 64;
  const int lr = lane & 15, kq = lane >> 4;
  const int sw = lr & 7;

  // ---- phase 0: deformable sampling for this block's 128 px -> As (SM), swizzled
  {
    const u16* kb = keyn + (size_t)b * (P_ * C_) + 2 * lane;
    const int pxbase = wave * 16;
    const size_t pixbase = (size_t)b * P_ + (size_t)h * W_ + w0 + pxbase;
    const int half64 = (lane >> 5) * 64;      // ci half (0/1) this lane's pair lives in
    const int gg = (lane >> 2) & 7;           // source 8-ch chunk within half
    const int e2 = (lane & 3) * 2;            // u16 offset within chunk
    for (int p = 0; p < 16; ++p) {
      const size_t pix = pixbase + p;
      float a0 = 0.f, a1 = 0.f;
#pragma unroll
      for (int k = 0; k < 4; ++k) {
        uint4 d = desc[pix * 4 + k];
        const int boff = (int)(d.x & 0xFFFFu) << 7;
        const int o01 = (int)((d.x >> 16) & 1u) << 7;
        const int o10 = (int)((d.x >> 17) & 1u) << 15;
        const u16* c0 = kb + boff;
        unsigned u00 = *(const unsigned*)(c0);
        unsigned u01 = *(const unsigned*)(c0 + o01);
        unsigned u10 = *(const unsigned*)(c0 + o10);
        unsigned u11 = *(const unsigned*)(c0 + o10 + o01);
        HU t01, t23; t01.u = d.y; t23.u = d.z;
        float2 wA = __half22float2(t01.h);
        float2 wB = __half22float2(t23.h);
        a0 = fmaf(wA.x, bf2f((u16)u00), a0);
        a0 = fmaf(wA.y, bf2f((u16)u01), a0);
        a0 = fmaf(wB.x, bf2f((u16)u10), a0);
        a0 = fmaf(wB.y, bf2f((u16)u11), a0);
        a1 = fmaf(wA.x, bf2f((u16)(u00 >> 16)), a1);
        a1 = fmaf(wA.y, bf2f((u16)(u01 >> 16)), a1);
        a1 = fmaf(wB.x, bf2f((u16)(u10 >> 16)), a1);
        a1 = fmaf(wB.y, bf2f((u16)(u11 >> 16)), a1);
      }
      const int px = pxbase + p;
      unsigned outu = ((unsigned)f2bf(a1) << 16) | (unsigned)f2bf(a0);
      // As[px][half*64 + (gg^(px&7))*8 + e2] — source chunk gg at swizzled position
      *(unsigned*)&SM[px * 128 + half64 + ((gg ^ (px & 7)) << 3) + e2] = outu;
    }
  }

  f32x4 acc[2][4];
#pragma unroll
  for (int i = 0; i < 2; i++)
#pragma unroll
    for (int j = 0; j < 4; j++) { f32x4 z = {0.f, 0.f, 0.f, 0.f}; acc[i][j] = z; }

  // ---- GEMM1: As(SM, 128px x 128ci) @ fw1 -> acc ; Bs staged per ci-half into T2
  for (int c = 0; c < 2; ++c) {
    const int ci0 = c << 6;
    const u16* Wb = W1 + ci0;
    __syncthreads();   // c=0: As ds_writes visible; c=1: protect T2 from c=0 readers
    for (int i = tid; i < 1024; i += 512) {
      int r = i >> 3, cb = i & 7;
      async16(Wb + r * 128 + ((cb ^ (r & 7)) << 3), T2 + i * 8);
    }
    __syncthreads();
#pragma unroll
    for (int ks = 0; ks < 2; ++ks) {
      const int kb = ks * 4 + kq;
      bf16x8 af[2], bfr[4];
#pragma unroll
      for (int i = 0; i < 2; i++)
        af[i] = *(const bf16x8*)&SM[(wm + i * 16 + lr) * 128 + ci0 + ((kb ^ sw) << 3)];
#pragma unroll
      for (int j = 0; j < 4; j++)
        bfr[j] = *(const bf16x8*)&T2[(wn + j * 16 + lr) * 64 + ((kb ^ sw) << 3)];
#pragma unroll
      for (int i = 0; i < 2; i++)
#pragma unroll
        for (int j = 0; j < 4; j++)
          acc[i][j] = __builtin_amdgcn_mfma_f32_16x16x32_bf16(af[i], bfr[j], acc[i][j], 0, 0, 0);
    }
  }
  __syncthreads();   // GEMM1 done: SM (As) and T2 (Bs) both dead

  // ---- stage fw2 into SM (async, overlaps GELU VALU work), GELU -> T2 (pitch 136)
  for (int i = tid; i < 2048; i += 512) {   // 128co x 16 chunks
    int r = i >> 4, sl = i & 15;
    int g = sl ^ (r & 7);
    async16(W2 + r * 128 + g * 8, SM + i * 8);
  }
#pragma unroll
  for (int i = 0; i < 2; i++)
#pragma unroll
    for (int j = 0; j < 4; j++) {
      const int co = wn + j * 16 + lr;
#pragma unroll
      for (int r = 0; r < 4; r++) {
        const int px = wm + i * 16 + kq * 4 + r;
        T2[px * 136 + co] = f2bf(gelu_f(acc[i][j][r] + b1[co]));
      }
    }
  __syncthreads();   // drains async W2 loads + T2 ds_writes

  // ---- GEMM2: T2(128px x 128k) @ fw2 -> acc
#pragma unroll
  for (int i = 0; i < 2; i++)
#pragma unroll
    for (int j = 0; j < 4; j++) { f32x4 z = {0.f, 0.f, 0.f, 0.f}; acc[i][j] = z; }
#pragma unroll
  for (int ks = 0; ks < 4; ++ks) {
    const int kc = ks * 4 + kq;
    bf16x8 af[2], bfr[4];
#pragma unroll
    for (int i = 0; i < 2; i++)
      af[i] = *(const bf16x8*)&T2[(wm + i * 16 + lr) * 136 + kc * 8];
#pragma unroll
    for (int j = 0; j < 4; j++) {
      int rr = wn + j * 16 + lr;
      bfr[j] = *(const bf16x8*)&SM[rr * 128 + (kc ^ (rr & 7)) * 8];
    }
#pragma unroll
    for (int i = 0; i < 2; i++)
#pragma unroll
      for (int j = 0; j < 4; j++)
        acc[i][j] = __builtin_amdgcn_mfma_f32_16x16x32_bf16(af[i], bfr[j], acc[i][j], 0, 0, 0);
  }

  // ---- residual epilogue (fp32 NCHW)
#pragma unroll
  for (int i = 0; i < 2; i++) {
#pragma unroll
    for (int j = 0; j < 4; j++) {
      const int co = wn + j * 16 + lr;
      const int w = w0 + wm + i * 16 + kq * 4;
      size_t idx = ((size_t)b * 128 + co) * (size_t)P_ + (size_t)h * W_ + w;
      float4 rv = *(const float4*)&resid[idx];
      float bi = b2[co];
      float4 ov;
      ov.x = rv.x + 0.3f * (acc[i][j][0] + bi);
      ov.y = rv.y + 0.3f * (acc[i][j][1] + bi);
      ov.z = rv.z + 0.3f * (acc[i][j][2] + bi);
      ov.w = rv.w + 0.3f * (acc[i][j][3] + bi);
      *(float4*)&out[idx] = ov;
    }
  }
}

extern "C" void kernel_launch(void* const* d_in, const int* in_sizes, int n_in,
                              void* d_out, int out_size, void* d_ws, size_t ws_size,
                              hipStream_t stream) {
  (void)in_sizes; (void)n_in; (void)out_size; (void)ws_size;
  const float* q   = (const float*)d_in[0];
  const float* key = (const float*)d_in[1];
  const float* ow1 = (const float*)d_in[2];
  const float* ob1 = (const float*)d_in[3];
  const float* ow2 = (const float*)d_in[4];
  const float* ob2 = (const float*)d_in[5];
  const float* ww1 = (const float*)d_in[6];
  const float* wb1 = (const float*)d_in[7];
  const float* ww2 = (const float*)d_in[8];
  const float* wb2 = (const float*)d_in[9];
  const float* fw1 = (const float*)d_in[10];
  const float* fb1 = (const float*)d_in[11];
  const float* fw2 = (const float*)d_in[12];
  const float* fb2 = (const float*)d_in[13];
  float* out = (float*)d_out;
  char* ws = (char*)d_ws;

  // workspace: qpad @0 (34.08MB, reused as desc after conv3_big); t1pad @34080768
  // (34.08MB); keyn @68161536 (33.55MB); w1b @101715968 (8.39MB);
  // wbuf @110104576 (471KB). peak 110.6MB. (agg buffer eliminated by sample_fuse.)
  u16* qpad  = (u16*)(ws);
  u16* t1pad = (u16*)(ws + 34080768);
  u16* keyn  = (u16*)(ws + 68161536);
  u16* w1b   = (u16*)(ws + 101715968);
  u16* wbuf  = (u16*)(ws + 110104576);
  uint4* desc = (uint4*)ws;        // qpad dead after conv3_big

  prologue<<<11176, 256, 0, stream>>>(q, key, ow1, ow2, ww1, fw1, fw2,
                                      qpad, keyn, t1pad, wbuf);
  conv3_big<<<1024, 512, 0, stream>>>(qpad, wbuf, ob1, wb1, t1pad, w1b);
  conv_off<<<512, 256, 0, stream>>>(t1pad, wbuf + 184320, ob2, w1b, ww2, wb2, desc);
  sample_fuse<<<dim3(2, 256, 2), 512, 0, stream>>>(desc, keyn, wbuf + 202752,
                                                   wbuf + 219136, fb1, fb2, q, out);
}

// Round 11
// 344.972 us; speedup vs baseline: 1.0801x; 1.0200x over previous
//
#include <hip/hip_runtime.h>
#include <hip/hip_fp16.h>

typedef unsigned short u16;
typedef __attribute__((ext_vector_type(8))) short bf16x8;
typedef __attribute__((ext_vector_type(4))) float f32x4;

constexpr int B_ = 2, C_ = 128, H_ = 256, W_ = 256, P_ = H_ * W_;
constexpr int HP_ = 258, WP_ = 258;

union HU { __half2 h; unsigned int u; };

__device__ __forceinline__ float bf2f(u16 u) {
  union { unsigned int i; float f; } v; v.i = ((unsigned int)u) << 16; return v.f;
}
__device__ __forceinline__ u16 f2bf(float f) {
  union { float f; unsigned int i; } v; v.f = f;
  return (u16)((v.i + 0x7fffu + ((v.i >> 16) & 1u)) >> 16);  // RNE
}
// tanh-form GELU via sigmoid; |dev from erf-GELU| <= ~5e-4
__device__ __forceinline__ float gelu_f(float x) {
  float u = x * (1.5957691216057308f + 0.071354816272f * x * x);
  return x / (1.0f + __expf(-u));
}

// async global->LDS, 16B per lane. LDS dest must be wave-uniform base + lane*16.
__device__ __forceinline__ void async16(const u16* g, u16* l) {
  __builtin_amdgcn_global_load_lds(
      (const __attribute__((address_space(1))) unsigned int*)g,
      (__attribute__((address_space(3))) unsigned int*)l, 16, 0, 0);
}

// ---------------- prologue: to_nhwc(q), to_nhwc(key), border-zero x2, repack ----------
// grid: [0,8192) nhwc transposes; [8192,10256) border; [10256,11176) repack
// Loads vectorized float4 (R8); NEW: stores paired into u32 (8 iters x 256B/wave-instr).
__global__ __launch_bounds__(256) void prologue(
    const float* __restrict__ q, const float* __restrict__ key,
    const float* __restrict__ ow1, const float* __restrict__ ow2,
    const float* __restrict__ ww1, const float* __restrict__ fw1,
    const float* __restrict__ fw2,
    u16* __restrict__ qpad, u16* __restrict__ keyn, u16* __restrict__ t1pad,
    u16* __restrict__ wb) {
  __shared__ u16 l[64 * 66];
  const int id = blockIdx.x, tid = threadIdx.x;
  if (id < 8192) {
    int z = id >> 10, r = id & 1023;
    int bx = r & 3, by = r >> 2;
    const float* in; u16* out; int OW, opad;
    if (z < 4) { in = q; out = qpad; OW = WP_; opad = 1; }
    else { z -= 4; in = key; out = keyn; OW = W_; opad = 0; }
    int b = z >> 1, c0 = (z & 1) * 64;
    int h = by, w0 = bx * 64;
    for (int it = 0; it < 4; ++it) {
      int lin = it * 256 + tid;                 // 1024 float4 quads
      int c = lin >> 4, w4 = (lin & 15) * 4;
      float4 v = *(const float4*)&in[(((size_t)b * C_ + c0 + c) * H_ + h) * W_ + w0 + w4];
      l[c * 66 + w4 + 0] = f2bf(v.x);
      l[c * 66 + w4 + 1] = f2bf(v.y);
      l[c * 66 + w4 + 2] = f2bf(v.z);
      l[c * 66 + w4 + 3] = f2bf(v.w);
    }
    __syncthreads();
    int OH = (opad ? HP_ : H_);
    for (int it = 0; it < 8; ++it) {
      int lin = it * 256 + tid;                 // 2048 u32 pairs
      int w = lin >> 5, c = (lin & 31) * 2;
      unsigned val = (unsigned)l[c * 66 + w] | ((unsigned)l[(c + 1) * 66 + w] << 16);
      *(unsigned*)&out[(((size_t)b * OH + h + opad) * OW + (w0 + w + opad)) * C_ + c0 + c] = val;
    }
  } else if (id < 10256) {
    int j = id - 8192;
    u16* buf = (j < 1032) ? qpad : t1pad;
    int idx = ((j < 1032) ? j : j - 1032) * 256 + tid;
    int c = idx & 127;
    int t = idx >> 7;
    int pos = t % 258;
    int side = (t / 258) & 3;
    int b = t / (258 * 4);
    int h, w;
    if (side == 0) { h = 0; w = pos; }
    else if (side == 1) { h = 257; w = pos; }
    else if (side == 2) { h = pos; w = 0; }
    else { h = pos; w = 257; }
    buf[(((size_t)b * HP_ + h) * WP_ + w) * C_ + c] = 0;
  } else {
    // repack weights into wbuf (bf16):
    // W1c @0: ow1+ww1 fragment-packed [tap][cq][g 10][kb 4][lr 16][e 8] = 184320
    // W2 @184320: ow2 packed GT=1, co 8->16 zero-pad = 18432
    // fw1 @202752 row-major [co][ci] 16384 ; fw2 @219136 row-major 16384
    int idx = (id - 10256) * 256 + tid;
    float v;
    if (idx < 184320) {
      int e = idx & 7, lr = (idx >> 3) & 15, kb = (idx >> 7) & 3;
      int t = idx >> 9;
      int g = t % 10, u = t / 10;
      int cq = u & 3, tap = u >> 2;
      int ci = cq * 32 + kb * 8 + e, co = g * 16 + lr;
      v = (co < 128) ? ow1[(co * 128 + ci) * 9 + tap]
                     : ww1[((co - 128) * 128 + ci) * 9 + tap];
    } else if (idx < 202752) {
      int j = idx - 184320;
      int e = j & 7, lr = (j >> 3) & 15, kb = (j >> 7) & 3;
      int cq = (j >> 9) & 3, tap = j >> 11;
      int ci = cq * 32 + kb * 8 + e, co = lr;
      v = (co < 8) ? ow2[(co * 128 + ci) * 9 + tap] : 0.0f;
    } else if (idx < 219136) {
      v = fw1[idx - 202752];
    } else {
      v = fw2[idx - 219136];
    }
    wb[idx] = f2bf(v);
  }
}

// ---------------- combined 3x3 conv (ow1 128->128 + ww1 128->32), band-tiled ----------
// R0-measured structure (74.5 us best): single As buffer, serial stage per ci-quarter,
// weights read directly from global per tap. R2 dbuf (+3 us) and R7 reg-prefetch
// (+13 us, 2x HBM traffic from disrupted write-combining) both REGRESSED — reverted.
__global__ __launch_bounds__(512, 4) void conv3_big(
    const u16* __restrict__ A, const u16* __restrict__ Wf,
    const float* __restrict__ bias1, const float* __restrict__ bias2,
    u16* __restrict__ outb, u16* __restrict__ outw) {
  constexpr int RPX = 36, ROWU = RPX * 32;          // u16 per row-plane = 1152
  __shared__ __align__(16) u16 As[6 * ROWU];        // 13,824 B
  const int tid = threadIdx.x, lane = tid & 63, wave = tid >> 6;  // 8 waves
  const int id = blockIdx.x;
  const int s = id >> 3;
  const int h0 = (((id & 7) << 3) | (s & 7)) << 2;  // 4-row band
  const int w0 = ((s >> 3) & 7) << 5;
  const int b = s >> 6;
  const int wr = wave >> 1, wc = wave & 1;          // wr: row 0..3, wc: co half
  const int wn = wc * 80;
  const int lr = lane & 15, kq = lane >> 4;
  const int gbase = wn >> 4;                        // 0 or 5

  int preA[2][3];
#pragma unroll
  for (int i = 0; i < 2; i++)
#pragma unroll
    for (int kx = 0; kx < 3; kx++) {
      int pxv = i * 16 + lr + kx;
      preA[i][kx] = (pxv * 4 + (kq ^ ((pxv >> 1) & 3))) * 8;  // u16 units
    }

  f32x4 acc[2][5];
#pragma unroll
  for (int i = 0; i < 2; i++)
#pragma unroll
    for (int j = 0; j < 5; j++) { f32x4 z = {0.f, 0.f, 0.f, 0.f}; acc[i][j] = z; }

  for (int cq = 0; cq < 4; ++cq) {
    const int ci0 = cq * 32;
    __syncthreads();
    for (int i = tid; i < 864; i += 512) {
      int ry = i / 144;
      int rem = i - ry * 144;
      int px = rem >> 2, c8 = rem & 3;
      int g = c8 ^ ((px >> 1) & 3);
      async16(A + ((size_t)(b * HP_ + h0 + ry) * WP_ + (w0 + px)) * 128 + ci0 + g * 8,
              As + i * 8);
    }
    __syncthreads();
#pragma unroll
    for (int tap = 0; tap < 9; ++tap) {
      const int ky = tap / 3, kx = tap % 3;
      bf16x8 bfr[5], af[2];
#pragma unroll
      for (int j = 0; j < 5; ++j)
        bfr[j] = *(const bf16x8*)&Wf[(size_t)((((tap * 4 + cq) * 10 + gbase + j) * 4 + kq) * 16 + lr) * 8];
#pragma unroll
      for (int i = 0; i < 2; ++i)
        af[i] = *(const bf16x8*)&As[(wr + ky) * ROWU + preA[i][kx]];
#pragma unroll
      for (int i = 0; i < 2; i++)
#pragma unroll
        for (int j = 0; j < 5; j++)
          acc[i][j] = __builtin_amdgcn_mfma_f32_16x16x32_bf16(af[i], bfr[j], acc[i][j], 0, 0, 0);
    }
  }

  const int h = h0 + wr;
#pragma unroll
  for (int i = 0; i < 2; i++) {
#pragma unroll
    for (int j = 0; j < 5; j++) {
      const int co = wn + j * 16 + lr;
#pragma unroll
      for (int r = 0; r < 4; r++) {
        const int w = w0 + i * 16 + kq * 4 + r;
        float v = acc[i][j][r];
        if (co < 128) {
          v = gelu_f(v + bias1[co]);
          outb[(((size_t)b * HP_ + h + 1) * WP_ + (w + 1)) * 128 + co] = f2bf(v);
        } else {
          v = gelu_f(v + bias2[co - 128]);
          outw[((size_t)b * P_ + (size_t)h * W_ + w) * 32 + (co - 128)] = f2bf(v);
        }
      }
    }
  }
}

// ---------------- offsets conv (3x3 128->8) + fused prep epilogue ---------------------
// BM=256 as 4 rows x 64 px; BN=16; wave = one row. 2 ci-quarters staged per round
// into As[2] (50.7KB LDS) — ~12 async16/thread issued before ONE drain, 2 rounds
// instead of 4 (R10: helped; conv_off dropped out of top-5). Epilogue unchanged.
__global__ __launch_bounds__(256) void conv_off(
    const u16* __restrict__ A, const u16* __restrict__ Wf,
    const float* __restrict__ bias,
    const u16* __restrict__ w1b, const float* __restrict__ ww2,
    const float* __restrict__ wb2, uint4* __restrict__ desc) {
  constexpr int RPX = 66, ROWU = RPX * 32;          // 2112 u16 per row-plane
  __shared__ __align__(16) u16 As[2][6 * ROWU];     // 2 x 25,344 B = 50,688 B
  float* off_lds = (float*)As;                      // reused after K-loop (256*9*4 B)
  const int tid = threadIdx.x, lane = tid & 63, wave = tid >> 6;
  const int id = blockIdx.x;
  const int s = id >> 3;
  const int h0 = (((id & 7) << 3) | (s & 7)) << 2;
  const int w0 = ((s >> 3) & 3) << 6;
  const int b = s >> 5;
  const int lr = lane & 15, kq = lane >> 4;

  int preA[4][3];
#pragma unroll
  for (int i = 0; i < 4; i++)
#pragma unroll
    for (int kx = 0; kx < 3; kx++) {
      int pxv = i * 16 + lr + kx;
      preA[i][kx] = (pxv * 4 + (kq ^ ((pxv >> 1) & 3))) * 8;
    }

  f32x4 acc[4];
#pragma unroll
  for (int i = 0; i < 4; i++) { f32x4 z = {0.f, 0.f, 0.f, 0.f}; acc[i] = z; }

  for (int r = 0; r < 2; ++r) {
    __syncthreads();                                // protect As from prev round readers
    // stage BOTH quarters of this round back-to-back: one deep pipeline, one drain
#pragma unroll
    for (int half = 0; half < 2; ++half) {
      const int ci0 = (r * 2 + half) * 32;
      for (int i = tid; i < 1584; i += 256) {
        int ry = i / 264;
        int rem = i - ry * 264;
        int px = rem >> 2, c8 = rem & 3;
        int g = c8 ^ ((px >> 1) & 3);
        async16(A + ((size_t)(b * HP_ + h0 + ry) * WP_ + (w0 + px)) * 128 + ci0 + g * 8,
                As[half] + i * 8);
      }
    }
    __syncthreads();                                // single drain per round
#pragma unroll
    for (int half = 0; half < 2; ++half) {
      const int cq = r * 2 + half;
      const u16* Ac = As[half];
#pragma unroll
      for (int tap = 0; tap < 9; ++tap) {
        const int ky = tap / 3, kx = tap % 3;
        bf16x8 bw = *(const bf16x8*)&Wf[(size_t)(((tap * 4 + cq) * 4 + kq) * 16 + lr) * 8];
        bf16x8 af[4];
#pragma unroll
        for (int i = 0; i < 4; ++i)
          af[i] = *(const bf16x8*)&Ac[(wave + ky) * ROWU + preA[i][kx]];
#pragma unroll
        for (int i = 0; i < 4; i++)
          acc[i] = __builtin_amdgcn_mfma_f32_16x16x32_bf16(af[i], bw, acc[i], 0, 0, 0);
      }
    }
  }

  __syncthreads();  // staging region dead; reuse as off_lds
#pragma unroll
  for (int i = 0; i < 4; i++) {
#pragma unroll
    for (int r = 0; r < 4; r++) {
      if (lr < 8) {
        int px = i * 16 + (lane >> 4) * 4 + r;
        off_lds[(wave * 64 + px) * 9 + lr] = acc[i][r] + bias[lr];
      }
    }
  }
  __syncthreads();

  // one pixel per thread
  const int pp = tid;
  const int h = h0 + (pp >> 6), w = w0 + (pp & 63);
  const int pix = b * P_ + h * W_ + w;
  const u16* wp = w1b + (size_t)pix * 32;
  float f[32];
#pragma unroll
  for (int i = 0; i < 32; i += 2) {
    unsigned u = *(const unsigned*)&wp[i];
    f[i] = bf2f((u16)u); f[i + 1] = bf2f((u16)(u >> 16));
  }
  float lg[4];
#pragma unroll
  for (int k = 0; k < 4; k++) {
    float sacc = wb2[k];
#pragma unroll
    for (int i = 0; i < 32; i++) sacc = fmaf(ww2[k * 32 + i], f[i], sacc);
    lg[k] = sacc;
  }
  float mx = fmaxf(fmaxf(lg[0], lg[1]), fmaxf(lg[2], lg[3]));
  float e[4], sum = 0.f;
#pragma unroll
  for (int k = 0; k < 4; k++) { e[k] = __expf(lg[k] - mx); sum += e[k]; }
  const float inv = 1.0f / sum;
#pragma unroll
  for (int k = 0; k < 4; k++) {
    float ox = off_lds[pp * 9 + 2 * k], oy = off_lds[pp * 9 + 2 * k + 1];
    float gx = (2.0f * w / 255.0f - 1.0f) + ox * (1.0f / 128.0f);
    float gy = (2.0f * h / 255.0f - 1.0f) + oy * (1.0f / 128.0f);
    gx = fminf(fmaxf(gx, -1.f), 1.f);
    gy = fminf(fmaxf(gy, -1.f), 1.f);
    float px = fminf(fmaxf((gx + 1.f) * 127.5f, 0.f), 255.f);
    float py = fminf(fmaxf((gy + 1.f) * 127.5f, 0.f), 255.f);
    int x0 = (int)px, y0 = (int)py;
    int x1 = min(x0 + 1, 255), y1 = min(y0 + 1, 255);
    float wx = px - x0, wy = py - y0;
    float wk = e[k] * inv;
    float w00 = (1.f - wx) * (1.f - wy) * wk, w01 = wx * (1.f - wy) * wk;
    float w10 = (1.f - wx) * wy * wk,         w11 = wx * wy * wk;
    HU t01, t23;
    t01.h = __floats2half2_rn(w00, w01);
    t23.h = __floats2half2_rn(w10, w11);
    uint4 d;
    d.x = (unsigned)(y0 * 256 + x0) | ((unsigned)(x1 - x0) << 16) | ((unsigned)(y1 - y0) << 17);
    d.y = t01.u; d.z = t23.u; d.w = 0;
    desc[(size_t)pix * 4 + k] = d;
  }
}

// ---------------- fused sample + 1x1 conv + GELU + 1x1 conv + residual ---------------
// Phase 0 (R10 counters: MfmaUtil 4%, VALUBusy 51%, HBM 25% -> VALU+latency bound):
// NEW — (1) desc path scalarized via readfirstlane (desc loads become s_load; addr
// math in SGPRs; was redundantly per-lane for wave-uniform data), (2) 2 pixels per
// iteration with all 32 gathers issued before use (2x MLP), (3) per-k partial sums +
// tree reduction (dep chain 1/4). GEMM/epilogue unchanged.
__global__ __launch_bounds__(512, 4) void sample_fuse(
    const uint4* __restrict__ desc, const u16* __restrict__ keyn,
    const u16* __restrict__ W1, const u16* __restrict__ W2,
    const float* __restrict__ b1, const float* __restrict__ b2,
    const float* __restrict__ resid, float* __restrict__ out) {
  __shared__ __align__(16) u16 SM[128 * 128];  // phase0/1: As full (px 128 x ci 128); phase2: W2
  __shared__ __align__(16) u16 T2[128 * 136];  // GEMM1: Bs half (8192 u16); then GELU tile
  const int tid = threadIdx.x, lane = tid & 63, wave = tid >> 6;  // 8 waves
  const int h = blockIdx.y, w0 = blockIdx.x * 128;
  const int b = blockIdx.z;
  const int wr = wave >> 1, wc = wave & 1;
  const int wm = wr * 32, wn = wc * 64;
  const int lr = lane & 15, kq = lane >> 4;
  const int sw = lr & 7;

  // ---- phase 0: deformable sampling for this block's 128 px -> As (SM), swizzled
  {
    const u16* kb = keyn + (size_t)b * (P_ * C_) + 2 * lane;
    const int pxbase = wave * 16;
    // wave-uniform pixel base in SGPR: desc loads scalarize to s_load
    const int pixs = __builtin_amdgcn_readfirstlane(b * P_ + h * W_ + w0 + pxbase);
    const int half64 = (lane >> 5) * 64;      // ci half (0/1) this lane's pair lives in
    const int gg = (lane >> 2) & 7;           // source 8-ch chunk within half
    const int e2 = (lane & 3) * 2;            // u16 offset within chunk
    for (int p = 0; p < 16; p += 2) {
      uint4 dA[4], dB[4];
#pragma unroll
      for (int k = 0; k < 4; ++k) dA[k] = desc[(size_t)(pixs + p) * 4 + k];
#pragma unroll
      for (int k = 0; k < 4; ++k) dB[k] = desc[(size_t)(pixs + p + 1) * 4 + k];
      unsigned vA[4][4], vB[4][4];
#pragma unroll
      for (int k = 0; k < 4; ++k) {
        const u16* c0 = kb + ((int)(dA[k].x & 0xFFFFu) << 7);
        const int o01 = (int)((dA[k].x >> 16) & 1u) << 7;
        const int o10 = (int)((dA[k].x >> 17) & 1u) << 15;
        vA[k][0] = *(const unsigned*)(c0);
        vA[k][1] = *(const unsigned*)(c0 + o01);
        vA[k][2] = *(const unsigned*)(c0 + o10);
        vA[k][3] = *(const unsigned*)(c0 + o10 + o01);
      }
#pragma unroll
      for (int k = 0; k < 4; ++k) {
        const u16* c0 = kb + ((int)(dB[k].x & 0xFFFFu) << 7);
        const int o01 = (int)((dB[k].x >> 16) & 1u) << 7;
        const int o10 = (int)((dB[k].x >> 17) & 1u) << 15;
        vB[k][0] = *(const unsigned*)(c0);
        vB[k][1] = *(const unsigned*)(c0 + o01);
        vB[k][2] = *(const unsigned*)(c0 + o10);
        vB[k][3] = *(const unsigned*)(c0 + o10 + o01);
      }
      float p0A[4], p1A[4], p0B[4], p1B[4];
#pragma unroll
      for (int k = 0; k < 4; ++k) {
        HU t01, t23; t01.u = dA[k].y; t23.u = dA[k].z;
        float2 wA = __half22float2(t01.h);
        float2 wB = __half22float2(t23.h);
        float s0 = wA.x * bf2f((u16)vA[k][0]);
        s0 = fmaf(wA.y, bf2f((u16)vA[k][1]), s0);
        s0 = fmaf(wB.x, bf2f((u16)vA[k][2]), s0);
        s0 = fmaf(wB.y, bf2f((u16)vA[k][3]), s0);
        p0A[k] = s0;
        float s1 = wA.x * bf2f((u16)(vA[k][0] >> 16));
        s1 = fmaf(wA.y, bf2f((u16)(vA[k][1] >> 16)), s1);
        s1 = fmaf(wB.x, bf2f((u16)(vA[k][2] >> 16)), s1);
        s1 = fmaf(wB.y, bf2f((u16)(vA[k][3] >> 16)), s1);
        p1A[k] = s1;
      }
#pragma unroll
      for (int k = 0; k < 4; ++k) {
        HU t01, t23; t01.u = dB[k].y; t23.u = dB[k].z;
        float2 wA = __half22float2(t01.h);
        float2 wB = __half22float2(t23.h);
        float s0 = wA.x * bf2f((u16)vB[k][0]);
        s0 = fmaf(wA.y, bf2f((u16)vB[k][1]), s0);
        s0 = fmaf(wB.x, bf2f((u16)vB[k][2]), s0);
        s0 = fmaf(wB.y, bf2f((u16)vB[k][3]), s0);
        p0B[k] = s0;
        float s1 = wA.x * bf2f((u16)(vB[k][0] >> 16));
        s1 = fmaf(wA.y, bf2f((u16)(vB[k][1] >> 16)), s1);
        s1 = fmaf(wB.x, bf2f((u16)(vB[k][2] >> 16)), s1);
        s1 = fmaf(wB.y, bf2f((u16)(vB[k][3] >> 16)), s1);
        p1B[k] = s1;
      }
      float a0A = (p0A[0] + p0A[1]) + (p0A[2] + p0A[3]);
      float a1A = (p1A[0] + p1A[1]) + (p1A[2] + p1A[3]);
      float a0B = (p0B[0] + p0B[1]) + (p0B[2] + p0B[3]);
      float a1B = (p1B[0] + p1B[1]) + (p1B[2] + p1B[3]);
      const int pxA = pxbase + p, pxB = pxbase + p + 1;
      unsigned uA = ((unsigned)f2bf(a1A) << 16) | (unsigned)f2bf(a0A);
      unsigned uB = ((unsigned)f2bf(a1B) << 16) | (unsigned)f2bf(a0B);
      // As[px][half*64 + (gg^(px&7))*8 + e2] — source chunk gg at swizzled position
      *(unsigned*)&SM[pxA * 128 + half64 + ((gg ^ (pxA & 7)) << 3) + e2] = uA;
      *(unsigned*)&SM[pxB * 128 + half64 + ((gg ^ (pxB & 7)) << 3) + e2] = uB;
    }
  }

  f32x4 acc[2][4];
#pragma unroll
  for (int i = 0; i < 2; i++)
#pragma unroll
    for (int j = 0; j < 4; j++) { f32x4 z = {0.f, 0.f, 0.f, 0.f}; acc[i][j] = z; }

  // ---- GEMM1: As(SM, 128px x 128ci) @ fw1 -> acc ; Bs staged per ci-half into T2
  for (int c = 0; c < 2; ++c) {
    const int ci0 = c << 6;
    const u16* Wb = W1 + ci0;
    __syncthreads();   // c=0: As ds_writes visible; c=1: protect T2 from c=0 readers
    for (int i = tid; i < 1024; i += 512) {
      int r = i >> 3, cb = i & 7;
      async16(Wb + r * 128 + ((cb ^ (r & 7)) << 3), T2 + i * 8);
    }
    __syncthreads();
#pragma unroll
    for (int ks = 0; ks < 2; ++ks) {
      const int kb = ks * 4 + kq;
      bf16x8 af[2], bfr[4];
#pragma unroll
      for (int i = 0; i < 2; i++)
        af[i] = *(const bf16x8*)&SM[(wm + i * 16 + lr) * 128 + ci0 + ((kb ^ sw) << 3)];
#pragma unroll
      for (int j = 0; j < 4; j++)
        bfr[j] = *(const bf16x8*)&T2[(wn + j * 16 + lr) * 64 + ((kb ^ sw) << 3)];
#pragma unroll
      for (int i = 0; i < 2; i++)
#pragma unroll
        for (int j = 0; j < 4; j++)
          acc[i][j] = __builtin_amdgcn_mfma_f32_16x16x32_bf16(af[i], bfr[j], acc[i][j], 0, 0, 0);
    }
  }
  __syncthreads();   // GEMM1 done: SM (As) and T2 (Bs) both dead

  // ---- stage fw2 into SM (async, overlaps GELU VALU work), GELU -> T2 (pitch 136)
  for (int i = tid; i < 2048; i += 512) {   // 128co x 16 chunks
    int r = i >> 4, sl = i & 15;
    int g = sl ^ (r & 7);
    async16(W2 + r * 128 + g * 8, SM + i * 8);
  }
#pragma unroll
  for (int i = 0; i < 2; i++)
#pragma unroll
    for (int j = 0; j < 4; j++) {
      const int co = wn + j * 16 + lr;
#pragma unroll
      for (int r = 0; r < 4; r++) {
        const int px = wm + i * 16 + kq * 4 + r;
        T2[px * 136 + co] = f2bf(gelu_f(acc[i][j][r] + b1[co]));
      }
    }
  __syncthreads();   // drains async W2 loads + T2 ds_writes

  // ---- GEMM2: T2(128px x 128k) @ fw2 -> acc
#pragma unroll
  for (int i = 0; i < 2; i++)
#pragma unroll
    for (int j = 0; j < 4; j++) { f32x4 z = {0.f, 0.f, 0.f, 0.f}; acc[i][j] = z; }
#pragma unroll
  for (int ks = 0; ks < 4; ++ks) {
    const int kc = ks * 4 + kq;
    bf16x8 af[2], bfr[4];
#pragma unroll
    for (int i = 0; i < 2; i++)
      af[i] = *(const bf16x8*)&T2[(wm + i * 16 + lr) * 136 + kc * 8];
#pragma unroll
    for (int j = 0; j < 4; j++) {
      int rr = wn + j * 16 + lr;
      bfr[j] = *(const bf16x8*)&SM[rr * 128 + (kc ^ (rr & 7)) * 8];
    }
#pragma unroll
    for (int i = 0; i < 2; i++)
#pragma unroll
      for (int j = 0; j < 4; j++)
        acc[i][j] = __builtin_amdgcn_mfma_f32_16x16x32_bf16(af[i], bfr[j], acc[i][j], 0, 0, 0);
  }

  // ---- residual epilogue (fp32 NCHW)
#pragma unroll
  for (int i = 0; i < 2; i++) {
#pragma unroll
    for (int j = 0; j < 4; j++) {
      const int co = wn + j * 16 + lr;
      const int w = w0 + wm + i * 16 + kq * 4;
      size_t idx = ((size_t)b * 128 + co) * (size_t)P_ + (size_t)h * W_ + w;
      float4 rv = *(const float4*)&resid[idx];
      float bi = b2[co];
      float4 ov;
      ov.x = rv.x + 0.3f * (acc[i][j][0] + bi);
      ov.y = rv.y + 0.3f * (acc[i][j][1] + bi);
      ov.z = rv.z + 0.3f * (acc[i][j][2] + bi);
      ov.w = rv.w + 0.3f * (acc[i][j][3] + bi);
      *(float4*)&out[idx] = ov;
    }
  }
}

extern "C" void kernel_launch(void* const* d_in, const int* in_sizes, int n_in,
                              void* d_out, int out_size, void* d_ws, size_t ws_size,
                              hipStream_t stream) {
  (void)in_sizes; (void)n_in; (void)out_size; (void)ws_size;
  const float* q   = (const float*)d_in[0];
  const float* key = (const float*)d_in[1];
  const float* ow1 = (const float*)d_in[2];
  const float* ob1 = (const float*)d_in[3];
  const float* ow2 = (const float*)d_in[4];
  const float* ob2 = (const float*)d_in[5];
  const float* ww1 = (const float*)d_in[6];
  const float* wb1 = (const float*)d_in[7];
  const float* ww2 = (const float*)d_in[8];
  const float* wb2 = (const float*)d_in[9];
  const float* fw1 = (const float*)d_in[10];
  const float* fb1 = (const float*)d_in[11];
  const float* fw2 = (const float*)d_in[12];
  const float* fb2 = (const float*)d_in[13];
  float* out = (float*)d_out;
  char* ws = (char*)d_ws;

  // workspace: qpad @0 (34.08MB, reused as desc after conv3_big); t1pad @34080768
  // (34.08MB); keyn @68161536 (33.55MB); w1b @101715968 (8.39MB);
  // wbuf @110104576 (471KB). peak 110.6MB. (agg buffer eliminated by sample_fuse.)
  u16* qpad  = (u16*)(ws);
  u16* t1pad = (u16*)(ws + 34080768);
  u16* keyn  = (u16*)(ws + 68161536);
  u16* w1b   = (u16*)(ws + 101715968);
  u16* wbuf  = (u16*)(ws + 110104576);
  uint4* desc = (uint4*)ws;        // qpad dead after conv3_big

  prologue<<<11176, 256, 0, stream>>>(q, key, ow1, ow2, ww1, fw1, fw2,
                                      qpad, keyn, t1pad, wbuf);
  conv3_big<<<1024, 512, 0, stream>>>(qpad, wbuf, ob1, wb1, t1pad, w1b);
  conv_off<<<512, 256, 0, stream>>>(t1pad, wbuf + 184320, ob2, w1b, ww2, wb2, desc);
  sample_fuse<<<dim3(2, 256, 2), 512, 0, stream>>>(desc, keyn, wbuf + 202752,
                                                   wbuf + 219136, fb1, fb2, q, out);
}

// Round 12
// 340.845 us; speedup vs baseline: 1.0932x; 1.0121x over previous
//
#include <hip/hip_runtime.h>
#include <hip/hip_fp16.h>

typedef unsigned short u16;
typedef __attribute__((ext_vector_type(8))) short bf16x8;
typedef __attribute__((ext_vector_type(4))) float f32x4;

constexpr int B_ = 2, C_ = 128, H_ = 256, W_ = 256, P_ = H_ * W_;
constexpr int HP_ = 258, WP_ = 258;

union HU { __half2 h; unsigned int u; };

__device__ __forceinline__ float bf2f(u16 u) {
  union { unsigned int i; float f; } v; v.i = ((unsigned int)u) << 16; return v.f;
}
__device__ __forceinline__ u16 f2bf(float f) {
  union { float f; unsigned int i; } v; v.f = f;
  return (u16)((v.i + 0x7fffu + ((v.i >> 16) & 1u)) >> 16);  // RNE
}
// tanh-form GELU via sigmoid; |dev from erf-GELU| <= ~5e-4
__device__ __forceinline__ float gelu_f(float x) {
  float u = x * (1.5957691216057308f + 0.071354816272f * x * x);
  return x / (1.0f + __expf(-u));
}

// async global->LDS, 16B per lane. LDS dest must be wave-uniform base + lane*16.
__device__ __forceinline__ void async16(const u16* g, u16* l) {
  __builtin_amdgcn_global_load_lds(
      (const __attribute__((address_space(1))) unsigned int*)g,
      (__attribute__((address_space(3))) unsigned int*)l, 16, 0, 0);
}

// ---------------- prologue: to_nhwc(q), to_nhwc(key), border-zero x2, repack ----------
// grid: [0,8192) nhwc transposes; [8192,10256) border; [10256,11176) repack
// Loads vectorized float4 (R8); stores paired into u32 (R11).
__global__ __launch_bounds__(256) void prologue(
    const float* __restrict__ q, const float* __restrict__ key,
    const float* __restrict__ ow1, const float* __restrict__ ow2,
    const float* __restrict__ ww1, const float* __restrict__ fw1,
    const float* __restrict__ fw2,
    u16* __restrict__ qpad, u16* __restrict__ keyn, u16* __restrict__ t1pad,
    u16* __restrict__ wb) {
  __shared__ u16 l[64 * 66];
  const int id = blockIdx.x, tid = threadIdx.x;
  if (id < 8192) {
    int z = id >> 10, r = id & 1023;
    int bx = r & 3, by = r >> 2;
    const float* in; u16* out; int OW, opad;
    if (z < 4) { in = q; out = qpad; OW = WP_; opad = 1; }
    else { z -= 4; in = key; out = keyn; OW = W_; opad = 0; }
    int b = z >> 1, c0 = (z & 1) * 64;
    int h = by, w0 = bx * 64;
    for (int it = 0; it < 4; ++it) {
      int lin = it * 256 + tid;                 // 1024 float4 quads
      int c = lin >> 4, w4 = (lin & 15) * 4;
      float4 v = *(const float4*)&in[(((size_t)b * C_ + c0 + c) * H_ + h) * W_ + w0 + w4];
      l[c * 66 + w4 + 0] = f2bf(v.x);
      l[c * 66 + w4 + 1] = f2bf(v.y);
      l[c * 66 + w4 + 2] = f2bf(v.z);
      l[c * 66 + w4 + 3] = f2bf(v.w);
    }
    __syncthreads();
    int OH = (opad ? HP_ : H_);
    for (int it = 0; it < 8; ++it) {
      int lin = it * 256 + tid;                 // 2048 u32 pairs
      int w = lin >> 5, c = (lin & 31) * 2;
      unsigned val = (unsigned)l[c * 66 + w] | ((unsigned)l[(c + 1) * 66 + w] << 16);
      *(unsigned*)&out[(((size_t)b * OH + h + opad) * OW + (w0 + w + opad)) * C_ + c0 + c] = val;
    }
  } else if (id < 10256) {
    int j = id - 8192;
    u16* buf = (j < 1032) ? qpad : t1pad;
    int idx = ((j < 1032) ? j : j - 1032) * 256 + tid;
    int c = idx & 127;
    int t = idx >> 7;
    int pos = t % 258;
    int side = (t / 258) & 3;
    int b = t / (258 * 4);
    int h, w;
    if (side == 0) { h = 0; w = pos; }
    else if (side == 1) { h = 257; w = pos; }
    else if (side == 2) { h = pos; w = 0; }
    else { h = pos; w = 257; }
    buf[(((size_t)b * HP_ + h) * WP_ + w) * C_ + c] = 0;
  } else {
    // repack weights into wbuf (bf16):
    // W1c @0: ow1+ww1 fragment-packed [tap][cq][g 10][kb 4][lr 16][e 8] = 184320
    // W2 @184320: ow2 packed GT=1, co 8->16 zero-pad = 18432
    // fw1 @202752 row-major [co][ci] 16384 ; fw2 @219136 row-major 16384
    int idx = (id - 10256) * 256 + tid;
    float v;
    if (idx < 184320) {
      int e = idx & 7, lr = (idx >> 3) & 15, kb = (idx >> 7) & 3;
      int t = idx >> 9;
      int g = t % 10, u = t / 10;
      int cq = u & 3, tap = u >> 2;
      int ci = cq * 32 + kb * 8 + e, co = g * 16 + lr;
      v = (co < 128) ? ow1[(co * 128 + ci) * 9 + tap]
                     : ww1[((co - 128) * 128 + ci) * 9 + tap];
    } else if (idx < 202752) {
      int j = idx - 184320;
      int e = j & 7, lr = (j >> 3) & 15, kb = (j >> 7) & 3;
      int cq = (j >> 9) & 3, tap = j >> 11;
      int ci = cq * 32 + kb * 8 + e, co = lr;
      v = (co < 8) ? ow2[(co * 128 + ci) * 9 + tap] : 0.0f;
    } else if (idx < 219136) {
      v = fw1[idx - 202752];
    } else {
      v = fw2[idx - 219136];
    }
    wb[idx] = f2bf(v);
  }
}

// ---------------- combined 3x3 conv (ow1 128->128 + ww1 128->32), band-tiled ----------
// R12: FIRST MEASUREMENT of weight-LDS-staging (written R2, infra-failed R3/R5/R6).
// Mechanism: per-wave global weight reads = 1.44MB/block = ~58% of per-CU L2 BW
// (R11 arithmetic). Staging the 10,240B (tap,cq) tile ONCE per block (double-buffered,
// prefetched one phase ahead) cuts weight L2 traffic 4x; bw reads become conflict-free
// stride-1 ds_read_b128. LDS 48.1KB -> 3 blocks/CU.
__global__ __launch_bounds__(512, 4) void conv3_big(
    const u16* __restrict__ A, const u16* __restrict__ Wf,
    const float* __restrict__ bias1, const float* __restrict__ bias2,
    u16* __restrict__ outb, u16* __restrict__ outw) {
  constexpr int RPX = 36, ROWU = RPX * 32;          // u16 per row-plane = 1152
  constexpr int WTILE = 5120;                       // u16 per (tap,cq) weight tile
  __shared__ __align__(16) u16 As[2][6 * ROWU];     // 2 x 13,824 B
  __shared__ __align__(16) u16 Wl[2][WTILE];        // 2 x 10,240 B
  const int tid = threadIdx.x, lane = tid & 63, wave = tid >> 6;  // 8 waves
  const int id = blockIdx.x;
  const int s = id >> 3;
  const int h0 = (((id & 7) << 3) | (s & 7)) << 2;  // 4-row band
  const int w0 = ((s >> 3) & 7) << 5;
  const int b = s >> 6;
  const int wr = wave >> 1, wc = wave & 1;          // wr: row 0..3, wc: co half
  const int wn = wc * 80;
  const int lr = lane & 15, kq = lane >> 4;
  const int gbase = wn >> 4;                        // 0 or 5

  int preA[2][3];
#pragma unroll
  for (int i = 0; i < 2; i++)
#pragma unroll
    for (int kx = 0; kx < 3; kx++) {
      int pxv = i * 16 + lr + kx;
      preA[i][kx] = (pxv * 4 + (kq ^ ((pxv >> 1) & 3))) * 8;  // u16 units
    }

  // A staging slots (i = tid, tid+512), hoisted out of the loop.
  size_t soff0, soff1;
  int doff0, doff1;
  const bool has2 = (tid + 512 < 864);
  {
    int i = tid;
    int ry = i / 144;
    int rem = i - ry * 144;
    int px = rem >> 2, c8 = rem & 3;
    int g = c8 ^ ((px >> 1) & 3);
    soff0 = ((size_t)(b * HP_ + h0 + ry) * WP_ + (w0 + px)) * 128 + g * 8;
    doff0 = i * 8;
  }
  {
    int i = (tid + 512 < 864) ? tid + 512 : tid;  // clamp: unused when !has2
    int ry = i / 144;
    int rem = i - ry * 144;
    int px = rem >> 2, c8 = rem & 3;
    int g = c8 ^ ((px >> 1) & 3);
    soff1 = ((size_t)(b * HP_ + h0 + ry) * WP_ + (w0 + px)) * 128 + g * 8;
    doff1 = i * 8;
  }
  // W staging: 640 x 16B per tile; slot tid (all) + tid+512 (tid<128).
  const bool whas2 = (tid < 128);
  const int wt0 = tid * 8, wt1 = (tid + 512) * 8;   // u16 offsets (wt1 unused if !whas2)

  f32x4 acc[2][5];
#pragma unroll
  for (int i = 0; i < 2; i++)
#pragma unroll
    for (int j = 0; j < 5; j++) { f32x4 z = {0.f, 0.f, 0.f, 0.f}; acc[i][j] = z; }

  // prologue: stage A(cq0) into As[0], W(tap0,cq0) into Wl[0]
  async16(A + soff0, As[0] + doff0);
  if (has2) async16(A + soff1, As[0] + doff1);
  async16(Wf + wt0, Wl[0] + wt0);
  if (whas2) async16(Wf + wt1, Wl[0] + wt1);
  __syncthreads();

  for (int cq = 0; cq < 4; ++cq) {
#pragma unroll
    for (int tap = 0; tap < 9; ++tap) {
      const int ky = tap / 3, kx = tap % 3;
      const int par = (cq + tap) & 1;               // phase parity (9 odd)
      // prefetch next weight tile into the other buffer
      if (tap < 8) {
        const u16* wsrc = Wf + (size_t)((tap + 1) * 4 + cq) * WTILE;
        u16* wdst = Wl[par ^ 1];
        async16(wsrc + wt0, wdst + wt0);
        if (whas2) async16(wsrc + wt1, wdst + wt1);
      } else if (cq < 3) {
        const u16* wsrc = Wf + (size_t)(cq + 1) * WTILE;
        u16* wdst = Wl[par ^ 1];
        async16(wsrc + wt0, wdst + wt0);
        if (whas2) async16(wsrc + wt1, wdst + wt1);
      }
      // prefetch next A quarter early in the cq (8 phases of cover)
      if (tap == 0 && cq < 3) {
        const int ci0 = (cq + 1) * 32;
        u16* dst = As[(cq + 1) & 1];
        async16(A + soff0 + ci0, dst + doff0);
        if (has2) async16(A + soff1 + ci0, dst + doff1);
      }
      const u16* Ac = As[cq & 1];
      const u16* Wc = Wl[par];
      bf16x8 bfr[5], af[2];
#pragma unroll
      for (int j = 0; j < 5; ++j)
        bfr[j] = *(const bf16x8*)&Wc[(gbase + j) * 512 + lane * 8];
#pragma unroll
      for (int i = 0; i < 2; ++i)
        af[i] = *(const bf16x8*)&Ac[(wr + ky) * ROWU + preA[i][kx]];
#pragma unroll
      for (int i = 0; i < 2; i++)
#pragma unroll
        for (int j = 0; j < 5; j++)
          acc[i][j] = __builtin_amdgcn_mfma_f32_16x16x32_bf16(af[i], bfr[j], acc[i][j], 0, 0, 0);
      // barrier: drains this phase's prefetch (covered by the 10 MFMAs + LDS reads)
      // and protects the W buffer we overwrite next phase.
      if (!(cq == 3 && tap == 8)) __syncthreads();
    }
  }

  const int h = h0 + wr;
#pragma unroll
  for (int i = 0; i < 2; i++) {
#pragma unroll
    for (int j = 0; j < 5; j++) {
      const int co = wn + j * 16 + lr;
#pragma unroll
      for (int r = 0; r < 4; r++) {
        const int w = w0 + i * 16 + kq * 4 + r;
        float v = acc[i][j][r];
        if (co < 128) {
          v = gelu_f(v + bias1[co]);
          outb[(((size_t)b * HP_ + h + 1) * WP_ + (w + 1)) * 128 + co] = f2bf(v);
        } else {
          v = gelu_f(v + bias2[co - 128]);
          outw[((size_t)b * P_ + (size_t)h * W_ + w) * 32 + (co - 128)] = f2bf(v);
        }
      }
    }
  }
}

// ---------------- offsets conv (3x3 128->8) + fused prep epilogue ---------------------
// BM=256 as 4 rows x 64 px; BN=16; wave = one row. 2 ci-quarters staged per round
// into As[2] (50.7KB LDS) — ~12 async16/thread issued before ONE drain, 2 rounds
// instead of 4 (R10: helped; conv_off dropped out of top-5). Epilogue unchanged.
__global__ __launch_bounds__(256) void conv_off(
    const u16* __restrict__ A, const u16* __restrict__ Wf,
    const float* __restrict__ bias,
    const u16* __restrict__ w1b, const float* __restrict__ ww2,
    const float* __restrict__ wb2, uint4* __restrict__ desc) {
  constexpr int RPX = 66, ROWU = RPX * 32;          // 2112 u16 per row-plane
  __shared__ __align__(16) u16 As[2][6 * ROWU];     // 2 x 25,344 B = 50,688 B
  float* off_lds = (float*)As;                      // reused after K-loop (256*9*4 B)
  const int tid = threadIdx.x, lane = tid & 63, wave = tid >> 6;
  const int id = blockIdx.x;
  const int s = id >> 3;
  const int h0 = (((id & 7) << 3) | (s & 7)) << 2;
  const int w0 = ((s >> 3) & 3) << 6;
  const int b = s >> 5;
  const int lr = lane & 15, kq = lane >> 4;

  int preA[4][3];
#pragma unroll
  for (int i = 0; i < 4; i++)
#pragma unroll
    for (int kx = 0; kx < 3; kx++) {
      int pxv = i * 16 + lr + kx;
      preA[i][kx] = (pxv * 4 + (kq ^ ((pxv >> 1) & 3))) * 8;
    }

  f32x4 acc[4];
#pragma unroll
  for (int i = 0; i < 4; i++) { f32x4 z = {0.f, 0.f, 0.f, 0.f}; acc[i] = z; }

  for (int r = 0; r < 2; ++r) {
    __syncthreads();                                // protect As from prev round readers
    // stage BOTH quarters of this round back-to-back: one deep pipeline, one drain
#pragma unroll
    for (int half = 0; half < 2; ++half) {
      const int ci0 = (r * 2 + half) * 32;
      for (int i = tid; i < 1584; i += 256) {
        int ry = i / 264;
        int rem = i - ry * 264;
        int px = rem >> 2, c8 = rem & 3;
        int g = c8 ^ ((px >> 1) & 3);
        async16(A + ((size_t)(b * HP_ + h0 + ry) * WP_ + (w0 + px)) * 128 + ci0 + g * 8,
                As[half] + i * 8);
      }
    }
    __syncthreads();                                // single drain per round
#pragma unroll
    for (int half = 0; half < 2; ++half) {
      const int cq = r * 2 + half;
      const u16* Ac = As[half];
#pragma unroll
      for (int tap = 0; tap < 9; ++tap) {
        const int ky = tap / 3, kx = tap % 3;
        bf16x8 bw = *(const bf16x8*)&Wf[(size_t)(((tap * 4 + cq) * 4 + kq) * 16 + lr) * 8];
        bf16x8 af[4];
#pragma unroll
        for (int i = 0; i < 4; ++i)
          af[i] = *(const bf16x8*)&Ac[(wave + ky) * ROWU + preA[i][kx]];
#pragma unroll
        for (int i = 0; i < 4; i++)
          acc[i] = __builtin_amdgcn_mfma_f32_16x16x32_bf16(af[i], bw, acc[i], 0, 0, 0);
      }
    }
  }

  __syncthreads();  // staging region dead; reuse as off_lds
#pragma unroll
  for (int i = 0; i < 4; i++) {
#pragma unroll
    for (int r = 0; r < 4; r++) {
      if (lr < 8) {
        int px = i * 16 + (lane >> 4) * 4 + r;
        off_lds[(wave * 64 + px) * 9 + lr] = acc[i][r] + bias[lr];
      }
    }
  }
  __syncthreads();

  // one pixel per thread
  const int pp = tid;
  const int h = h0 + (pp >> 6), w = w0 + (pp & 63);
  const int pix = b * P_ + h * W_ + w;
  const u16* wp = w1b + (size_t)pix * 32;
  float f[32];
#pragma unroll
  for (int i = 0; i < 32; i += 2) {
    unsigned u = *(const unsigned*)&wp[i];
    f[i] = bf2f((u16)u); f[i + 1] = bf2f((u16)(u >> 16));
  }
  float lg[4];
#pragma unroll
  for (int k = 0; k < 4; k++) {
    float sacc = wb2[k];
#pragma unroll
    for (int i = 0; i < 32; i++) sacc = fmaf(ww2[k * 32 + i], f[i], sacc);
    lg[k] = sacc;
  }
  float mx = fmaxf(fmaxf(lg[0], lg[1]), fmaxf(lg[2], lg[3]));
  float e[4], sum = 0.f;
#pragma unroll
  for (int k = 0; k < 4; k++) { e[k] = __expf(lg[k] - mx); sum += e[k]; }
  const float inv = 1.0f / sum;
#pragma unroll
  for (int k = 0; k < 4; k++) {
    float ox = off_lds[pp * 9 + 2 * k], oy = off_lds[pp * 9 + 2 * k + 1];
    float gx = (2.0f * w / 255.0f - 1.0f) + ox * (1.0f / 128.0f);
    float gy = (2.0f * h / 255.0f - 1.0f) + oy * (1.0f / 128.0f);
    gx = fminf(fmaxf(gx, -1.f), 1.f);
    gy = fminf(fmaxf(gy, -1.f), 1.f);
    float px = fminf(fmaxf((gx + 1.f) * 127.5f, 0.f), 255.f);
    float py = fminf(fmaxf((gy + 1.f) * 127.5f, 0.f), 255.f);
    int x0 = (int)px, y0 = (int)py;
    int x1 = min(x0 + 1, 255), y1 = min(y0 + 1, 255);
    float wx = px - x0, wy = py - y0;
    float wk = e[k] * inv;
    float w00 = (1.f - wx) * (1.f - wy) * wk, w01 = wx * (1.f - wy) * wk;
    float w10 = (1.f - wx) * wy * wk,         w11 = wx * wy * wk;
    HU t01, t23;
    t01.h = __floats2half2_rn(w00, w01);
    t23.h = __floats2half2_rn(w10, w11);
    uint4 d;
    d.x = (unsigned)(y0 * 256 + x0) | ((unsigned)(x1 - x0) << 16) | ((unsigned)(y1 - y0) << 17);
    d.y = t01.u; d.z = t23.u; d.w = 0;
    desc[(size_t)pix * 4 + k] = d;
  }
}

// ---------------- fused sample + 1x1 conv + GELU + 1x1 conv + residual ---------------
// Phase 0 scalarized desc path + 2-px pipeline + partial-sum tree (R11: sample_fuse
// dropped out of top-5, 82 -> <73.5 us). GEMM/epilogue unchanged.
__global__ __launch_bounds__(512, 4) void sample_fuse(
    const uint4* __restrict__ desc, const u16* __restrict__ keyn,
    const u16* __restrict__ W1, const u16* __restrict__ W2,
    const float* __restrict__ b1, const float* __restrict__ b2,
    const float* __restrict__ resid, float* __restrict__ out) {
  __shared__ __align__(16) u16 SM[128 * 128];  // phase0/1: As full (px 128 x ci 128); phase2: W2
  __shared__ __align__(16) u16 T2[128 * 136];  // GEMM1: Bs half (8192 u16); then GELU tile
  const int tid = threadIdx.x, lane = tid & 63, wave = tid >> 6;  // 8 waves
  const int h = blockIdx.y, w0 = blockIdx.x * 128;
  const int b = blockIdx.z;
  const int wr = wave >> 1, wc = wave & 1;
  const int wm = wr * 32, wn = wc * 64;
  const int lr = lane & 15, kq = lane >> 4;
  const int sw = lr & 7;

  // ---- phase 0: deformable sampling for this block's 128 px -> As (SM), swizzled
  {
    const u16* kb = keyn + (size_t)b * (P_ * C_) + 2 * lane;
    const int pxbase = wave * 16;
    // wave-uniform pixel base in SGPR: desc loads scalarize to s_load
    const int pixs = __builtin_amdgcn_readfirstlane(b * P_ + h * W_ + w0 + pxbase);
    const int half64 = (lane >> 5) * 64;      // ci half (0/1) this lane's pair lives in
    const int gg = (lane >> 2) & 7;           // source 8-ch chunk within half
    const int e2 = (lane & 3) * 2;            // u16 offset within chunk
    for (int p = 0; p < 16; p += 2) {
      uint4 dA[4], dB[4];
#pragma unroll
      for (int k = 0; k < 4; ++k) dA[k] = desc[(size_t)(pixs + p) * 4 + k];
#pragma unroll
      for (int k = 0; k < 4; ++k) dB[k] = desc[(size_t)(pixs + p + 1) * 4 + k];
      unsigned vA[4][4], vB[4][4];
#pragma unroll
      for (int k = 0; k < 4; ++k) {
        const u16* c0 = kb + ((int)(dA[k].x & 0xFFFFu) << 7);
        const int o01 = (int)((dA[k].x >> 16) & 1u) << 7;
        const int o10 = (int)((dA[k].x >> 17) & 1u) << 15;
        vA[k][0] = *(const unsigned*)(c0);
        vA[k][1] = *(const unsigned*)(c0 + o01);
        vA[k][2] = *(const unsigned*)(c0 + o10);
        vA[k][3] = *(const unsigned*)(c0 + o10 + o01);
      }
#pragma unroll
      for (int k = 0; k < 4; ++k) {
        const u16* c0 = kb + ((int)(dB[k].x & 0xFFFFu) << 7);
        const int o01 = (int)((dB[k].x >> 16) & 1u) << 7;
        const int o10 = (int)((dB[k].x >> 17) & 1u) << 15;
        vB[k][0] = *(const unsigned*)(c0);
        vB[k][1] = *(const unsigned*)(c0 + o01);
        vB[k][2] = *(const unsigned*)(c0 + o10);
        vB[k][3] = *(const unsigned*)(c0 + o10 + o01);
      }
      float p0A[4], p1A[4], p0B[4], p1B[4];
#pragma unroll
      for (int k = 0; k < 4; ++k) {
        HU t01, t23; t01.u = dA[k].y; t23.u = dA[k].z;
        float2 wA = __half22float2(t01.h);
        float2 wB = __half22float2(t23.h);
        float s0 = wA.x * bf2f((u16)vA[k][0]);
        s0 = fmaf(wA.y, bf2f((u16)vA[k][1]), s0);
        s0 = fmaf(wB.x, bf2f((u16)vA[k][2]), s0);
        s0 = fmaf(wB.y, bf2f((u16)vA[k][3]), s0);
        p0A[k] = s0;
        float s1 = wA.x * bf2f((u16)(vA[k][0] >> 16));
        s1 = fmaf(wA.y, bf2f((u16)(vA[k][1] >> 16)), s1);
        s1 = fmaf(wB.x, bf2f((u16)(vA[k][2] >> 16)), s1);
        s1 = fmaf(wB.y, bf2f((u16)(vA[k][3] >> 16)), s1);
        p1A[k] = s1;
      }
#pragma unroll
      for (int k = 0; k < 4; ++k) {
        HU t01, t23; t01.u = dB[k].y; t23.u = dB[k].z;
        float2 wA = __half22float2(t01.h);
        float2 wB = __half22float2(t23.h);
        float s0 = wA.x * bf2f((u16)vB[k][0]);
        s0 = fmaf(wA.y, bf2f((u16)vB[k][1]), s0);
        s0 = fmaf(wB.x, bf2f((u16)vB[k][2]), s0);
        s0 = fmaf(wB.y, bf2f((u16)vB[k][3]), s0);
        p0B[k] = s0;
        float s1 = wA.x * bf2f((u16)(vB[k][0] >> 16));
        s1 = fmaf(wA.y, bf2f((u16)(vB[k][1] >> 16)), s1);
        s1 = fmaf(wB.x, bf2f((u16)(vB[k][2] >> 16)), s1);
        s1 = fmaf(wB.y, bf2f((u16)(vB[k][3] >> 16)), s1);
        p1B[k] = s1;
      }
      float a0A = (p0A[0] + p0A[1]) + (p0A[2] + p0A[3]);
      float a1A = (p1A[0] + p1A[1]) + (p1A[2] + p1A[3]);
      float a0B = (p0B[0] + p0B[1]) + (p0B[2] + p0B[3]);
      float a1B = (p1B[0] + p1B[1]) + (p1B[2] + p1B[3]);
      const int pxA = pxbase + p, pxB = pxbase + p + 1;
      unsigned uA = ((unsigned)f2bf(a1A) << 16) | (unsigned)f2bf(a0A);
      unsigned uB = ((unsigned)f2bf(a1B) << 16) | (unsigned)f2bf(a0B);
      // As[px][half*64 + (gg^(px&7))*8 + e2] — source chunk gg at swizzled position
      *(unsigned*)&SM[pxA * 128 + half64 + ((gg ^ (pxA & 7)) << 3) + e2] = uA;
      *(unsigned*)&SM[pxB * 128 + half64 + ((gg ^ (pxB & 7)) << 3) + e2] = uB;
    }
  }

  f32x4 acc[2][4];
#pragma unroll
  for (int i = 0; i < 2; i++)
#pragma unroll
    for (int j = 0; j < 4; j++) { f32x4 z = {0.f, 0.f, 0.f, 0.f}; acc[i][j] = z; }

  // ---- GEMM1: As(SM, 128px x 128ci) @ fw1 -> acc ; Bs staged per ci-half into T2
  for (int c = 0; c < 2; ++c) {
    const int ci0 = c << 6;
    const u16* Wb = W1 + ci0;
    __syncthreads();   // c=0: As ds_writes visible; c=1: protect T2 from c=0 readers
    for (int i = tid; i < 1024; i += 512) {
      int r = i >> 3, cb = i & 7;
      async16(Wb + r * 128 + ((cb ^ (r & 7)) << 3), T2 + i * 8);
    }
    __syncthreads();
#pragma unroll
    for (int ks = 0; ks < 2; ++ks) {
      const int kb = ks * 4 + kq;
      bf16x8 af[2], bfr[4];
#pragma unroll
      for (int i = 0; i < 2; i++)
        af[i] = *(const bf16x8*)&SM[(wm + i * 16 + lr) * 128 + ci0 + ((kb ^ sw) << 3)];
#pragma unroll
      for (int j = 0; j < 4; j++)
        bfr[j] = *(const bf16x8*)&T2[(wn + j * 16 + lr) * 64 + ((kb ^ sw) << 3)];
#pragma unroll
      for (int i = 0; i < 2; i++)
#pragma unroll
        for (int j = 0; j < 4; j++)
          acc[i][j] = __builtin_amdgcn_mfma_f32_16x16x32_bf16(af[i], bfr[j], acc[i][j], 0, 0, 0);
    }
  }
  __syncthreads();   // GEMM1 done: SM (As) and T2 (Bs) both dead

  // ---- stage fw2 into SM (async, overlaps GELU VALU work), GELU -> T2 (pitch 136)
  for (int i = tid; i < 2048; i += 512) {   // 128co x 16 chunks
    int r = i >> 4, sl = i & 15;
    int g = sl ^ (r & 7);
    async16(W2 + r * 128 + g * 8, SM + i * 8);
  }
#pragma unroll
  for (int i = 0; i < 2; i++)
#pragma unroll
    for (int j = 0; j < 4; j++) {
      const int co = wn + j * 16 + lr;
#pragma unroll
      for (int r = 0; r < 4; r++) {
        const int px = wm + i * 16 + kq * 4 + r;
        T2[px * 136 + co] = f2bf(gelu_f(acc[i][j][r] + b1[co]));
      }
    }
  __syncthreads();   // drains async W2 loads + T2 ds_writes

  // ---- GEMM2: T2(128px x 128k) @ fw2 -> acc
#pragma unroll
  for (int i = 0; i < 2; i++)
#pragma unroll
    for (int j = 0; j < 4; j++) { f32x4 z = {0.f, 0.f, 0.f, 0.f}; acc[i][j] = z; }
#pragma unroll
  for (int ks = 0; ks < 4; ++ks) {
    const int kc = ks * 4 + kq;
    bf16x8 af[2], bfr[4];
#pragma unroll
    for (int i = 0; i < 2; i++)
      af[i] = *(const bf16x8*)&T2[(wm + i * 16 + lr) * 136 + kc * 8];
#pragma unroll
    for (int j = 0; j < 4; j++) {
      int rr = wn + j * 16 + lr;
      bfr[j] = *(const bf16x8*)&SM[rr * 128 + (kc ^ (rr & 7)) * 8];
    }
#pragma unroll
    for (int i = 0; i < 2; i++)
#pragma unroll
      for (int j = 0; j < 4; j++)
        acc[i][j] = __builtin_amdgcn_mfma_f32_16x16x32_bf16(af[i], bfr[j], acc[i][j], 0, 0, 0);
  }

  // ---- residual epilogue (fp32 NCHW)
#pragma unroll
  for (int i = 0; i < 2; i++) {
#pragma unroll
    for (int j = 0; j < 4; j++) {
      const int co = wn + j * 16 + lr;
      const int w = w0 + wm + i * 16 + kq * 4;
      size_t idx = ((size_t)b * 128 + co) * (size_t)P_ + (size_t)h * W_ + w;
      float4 rv = *(const float4*)&resid[idx];
      float bi = b2[co];
      float4 ov;
      ov.x = rv.x + 0.3f * (acc[i][j][0] + bi);
      ov.y = rv.y + 0.3f * (acc[i][j][1] + bi);
      ov.z = rv.z + 0.3f * (acc[i][j][2] + bi);
      ov.w = rv.w + 0.3f * (acc[i][j][3] + bi);
      *(float4*)&out[idx] = ov;
    }
  }
}

extern "C" void kernel_launch(void* const* d_in, const int* in_sizes, int n_in,
                              void* d_out, int out_size, void* d_ws, size_t ws_size,
                              hipStream_t stream) {
  (void)in_sizes; (void)n_in; (void)out_size; (void)ws_size;
  const float* q   = (const float*)d_in[0];
  const float* key = (const float*)d_in[1];
  const float* ow1 = (const float*)d_in[2];
  const float* ob1 = (const float*)d_in[3];
  const float* ow2 = (const float*)d_in[4];
  const float* ob2 = (const float*)d_in[5];
  const float* ww1 = (const float*)d_in[6];
  const float* wb1 = (const float*)d_in[7];
  const float* ww2 = (const float*)d_in[8];
  const float* wb2 = (const float*)d_in[9];
  const float* fw1 = (const float*)d_in[10];
  const float* fb1 = (const float*)d_in[11];
  const float* fw2 = (const float*)d_in[12];
  const float* fb2 = (const float*)d_in[13];
  float* out = (float*)d_out;
  char* ws = (char*)d_ws;

  // workspace: qpad @0 (34.08MB, reused as desc after conv3_big); t1pad @34080768
  // (34.08MB); keyn @68161536 (33.55MB); w1b @101715968 (8.39MB);
  // wbuf @110104576 (471KB). peak 110.6MB. (agg buffer eliminated by sample_fuse.)
  u16* qpad  = (u16*)(ws);
  u16* t1pad = (u16*)(ws + 34080768);
  u16* keyn  = (u16*)(ws + 68161536);
  u16* w1b   = (u16*)(ws + 101715968);
  u16* wbuf  = (u16*)(ws + 110104576);
  uint4* desc = (uint4*)ws;        // qpad dead after conv3_big

  prologue<<<11176, 256, 0, stream>>>(q, key, ow1, ow2, ww1, fw1, fw2,
                                      qpad, keyn, t1pad, wbuf);
  conv3_big<<<1024, 512, 0, stream>>>(qpad, wbuf, ob1, wb1, t1pad, w1b);
  conv_off<<<512, 256, 0, stream>>>(t1pad, wbuf + 184320, ob2, w1b, ww2, wb2, desc);
  sample_fuse<<<dim3(2, 256, 2), 512, 0, stream>>>(desc, keyn, wbuf + 202752,
                                                   wbuf + 219136, fb1, fb2, q, out);
}